// Round 2
// baseline (1610.985 us; speedup 1.0000x reference)
//
#include <hip/hip_runtime.h>
#include <hip/hip_bf16.h>
#include <math.h>

typedef __hip_bfloat16 bf16;
typedef __attribute__((ext_vector_type(8))) short bf16x8;   // 8 bf16 (4 VGPRs) per guide §3
typedef __attribute__((ext_vector_type(4))) float f32x4;

__device__ __forceinline__ float b2f(bf16 x){ return __bfloat162float(x); }
__device__ __forceinline__ bf16  f2b(float x){ return __float2bfloat16(x); }
__device__ __forceinline__ float bu2f_lo(unsigned u){ return __uint_as_float(u << 16); }
__device__ __forceinline__ float bu2f_hi(unsigned u){ return __uint_as_float(u & 0xffff0000u); }

#define NTOK 197
#define NBATCH 64
#define NHEAD 8
#define DHEAD 96
#define DIMC 768
#define NROWS (NBATCH * NTOK)   // 12608

// ---------------- workspace layout (bytes) ----------------
// p (841x8 f32)                     @ 0          (32 KB reserved)
// h (12608x768 bf16)                @ OFF_H
// q (64x8x197x96 bf16)              @ OFF_Q   -> later x1 (f32, spans q+k exactly)
// k                                 @ OFF_K
// v                                 @ OFF_V   -> later mid (bf16, spans v+ao exactly)
// ao (12608x768 bf16)               @ OFF_AO
#define OFF_H  32768ull
#define SZ_H   19365888ull                  // 12608*768*2
#define OFF_Q  (OFF_H + SZ_H)
#define OFF_K  (OFF_Q + SZ_H)
#define OFF_V  (OFF_K + SZ_H)
#define OFF_AO (OFF_V + SZ_H)               // end ~96.9 MB

// ---------------- position-bias MLP (841 rows, tiny, all f32) ----------------
__global__ __launch_bounds__(64) void pos_mlp(
    const float* __restrict__ biases, const float* __restrict__ pp_w, const float* __restrict__ pp_b,
    const float* __restrict__ ln1w, const float* __restrict__ ln1b,
    const float* __restrict__ f1w,  const float* __restrict__ f1b,
    const float* __restrict__ ln2w, const float* __restrict__ ln2b,
    const float* __restrict__ f2w,  const float* __restrict__ f2b,
    const float* __restrict__ ln3w, const float* __restrict__ ln3b,
    const float* __restrict__ f3w,  const float* __restrict__ f3b,
    float* __restrict__ pout)
{
    const int row = blockIdx.x, j = threadIdx.x;
    __shared__ float va[48], vb[48];
    float b0 = biases[row*2], b1 = biases[row*2+1];
    if (j < 48) va[j] = b0*pp_w[j*2] + b1*pp_w[j*2+1] + pp_b[j];
    __syncthreads();
    {   // stage 1: LN(va)->relu->fc1 -> vb
        float s=0.f, s2=0.f;
        for (int i=0;i<48;i++){ float t=va[i]; s+=t; s2+=t*t; }
        float mean=s*(1.f/48.f), var=s2*(1.f/48.f)-mean*mean, inv=rsqrtf(var+1e-5f);
        float r=0.f;
        if (j < 48){
            r = f1b[j];
            for (int i=0;i<48;i++){
                float t = fmaxf((va[i]-mean)*inv*ln1w[i] + ln1b[i], 0.f);
                r += t * f1w[j*48+i];
            }
        }
        __syncthreads();
        if (j < 48) vb[j] = r;
    }
    __syncthreads();
    {   // stage 2: LN(vb)->relu->fc2 -> va
        float s=0.f, s2=0.f;
        for (int i=0;i<48;i++){ float t=vb[i]; s+=t; s2+=t*t; }
        float mean=s*(1.f/48.f), var=s2*(1.f/48.f)-mean*mean, inv=rsqrtf(var+1e-5f);
        float r=0.f;
        if (j < 48){
            r = f2b[j];
            for (int i=0;i<48;i++){
                float t = fmaxf((vb[i]-mean)*inv*ln2w[i] + ln2b[i], 0.f);
                r += t * f2w[j*48+i];
            }
        }
        __syncthreads();
        if (j < 48) va[j] = r;
    }
    __syncthreads();
    {   // stage 3: LN(va)->relu->fc3 (8 outs)
        float s=0.f, s2=0.f;
        for (int i=0;i<48;i++){ float t=va[i]; s+=t; s2+=t*t; }
        float mean=s*(1.f/48.f), var=s2*(1.f/48.f)-mean*mean, inv=rsqrtf(var+1e-5f);
        if (j < 8){
            float r = f3b[j];
            for (int i=0;i<48;i++){
                float t = fmaxf((va[i]-mean)*inv*ln3w[i] + ln3b[i], 0.f);
                r += t * f3w[j*48+i];
            }
            pout[row*8+j] = r;
        }
    }
}

// ---------------- LayerNorm over 768 (f32 in, bf16 out), one block per row ----------------
__global__ __launch_bounds__(256) void ln768(
    const float* __restrict__ x, const float* __restrict__ w, const float* __restrict__ b,
    bf16* __restrict__ out)
{
    const int row = blockIdx.x, tid = threadIdx.x;
    const int wv = tid >> 6, ln = tid & 63;
    __shared__ float rs[4], rs2[4];
    const float* xr = x + (size_t)row * DIMC;
    float v0 = xr[tid], v1 = xr[tid+256], v2 = xr[tid+512];
    float s = v0+v1+v2, s2 = v0*v0+v1*v1+v2*v2;
    #pragma unroll
    for (int off=32; off; off>>=1){ s += __shfl_xor(s,off,64); s2 += __shfl_xor(s2,off,64); }
    if (ln == 0){ rs[wv]=s; rs2[wv]=s2; }
    __syncthreads();
    s = rs[0]+rs[1]+rs[2]+rs[3]; s2 = rs2[0]+rs2[1]+rs2[2]+rs2[3];
    float mean = s*(1.f/768.f), var = s2*(1.f/768.f) - mean*mean;
    float inv = rsqrtf(var + 1e-5f);
    size_t base = (size_t)row * DIMC;
    out[base+tid]     = f2b((v0-mean)*inv*w[tid]     + b[tid]);
    out[base+tid+256] = f2b((v1-mean)*inv*w[tid+256] + b[tid+256]);
    out[base+tid+512] = f2b((v2-mean)*inv*w[tid+512] + b[tid+512]);
}

// ---------------- l2-normalize q,k rows (96 elems, bf16 in-place), wave per row ----------------
__global__ __launch_bounds__(256) void l2norm_qk(bf16* __restrict__ q, bf16* __restrict__ k)
{
    const int wv = threadIdx.x >> 6, ln = threadIdx.x & 63;
    const size_t NR = (size_t)NBATCH*NHEAD*NTOK;  // 100864
    size_t row = (size_t)blockIdx.x * 4 + wv;     // 201728 total
    bf16* ptr = (row < NR) ? (q + row*DHEAD) : (k + (row-NR)*DHEAD);
    float x0 = b2f(ptr[ln]);
    float x1 = (ln < 32) ? b2f(ptr[64+ln]) : 0.f;
    float ss = x0*x0 + x1*x1;
    #pragma unroll
    for (int off=32; off; off>>=1) ss += __shfl_xor(ss,off,64);
    float inv = 1.f / fmaxf(sqrtf(ss), 1e-12f);
    ptr[ln] = f2b(x0*inv);
    if (ln < 32) ptr[64+ln] = f2b(x1*inv);
}

// ---------------- fused attention: scores -> premix -> mask -> softmax -> postmix -> @V ----------------
__global__ __launch_bounds__(256) void attn_fused(
    const bf16* __restrict__ q, const bf16* __restrict__ k, const bf16* __restrict__ v,
    const float* __restrict__ p, const int* __restrict__ rel_idx,
    const float* __restrict__ prior_adj, const float* __restrict__ scale,
    const float* __restrict__ pre_w, const float* __restrict__ post_w,
    bf16* __restrict__ ao)
{
    const int n = blockIdx.x;     // token
    const int b = blockIdx.y;     // batch
    const int tid = threadIdx.x;
    const int wv = tid >> 6, ln = tid & 63;
    __shared__ float qrow[DIMC];         // 8 heads x 96
    __shared__ float s[NHEAD*NTOK];      // raw scores -> later postmixed attn
    __shared__ float s2[NHEAD*NTOK];     // premixed/masked -> softmaxed
    for (int i=tid; i<DIMC; i+=256){
        int h = i/96, di = i - h*96;
        qrow[i] = b2f(q[(((size_t)b*NHEAD+h)*NTOK+n)*DHEAD + di]);
    }
    __syncthreads();
    // scores: s[h][m] = (qn . kn)*min(scale[h],100) + p[rel_idx[n][m]][h]
    for (int idx=tid; idx<NHEAD*NTOK; idx+=256){
        int h = idx/NTOK, m = idx - h*NTOK;
        const uint4* kr = reinterpret_cast<const uint4*>(k + (((size_t)b*NHEAD+h)*NTOK+m)*DHEAD);
        float acc = 0.f;
        #pragma unroll
        for (int t=0;t<12;t++){
            uint4 u = kr[t];
            const float* qh = qrow + h*96 + t*8;
            acc += qh[0]*bu2f_lo(u.x) + qh[1]*bu2f_hi(u.x)
                 + qh[2]*bu2f_lo(u.y) + qh[3]*bu2f_hi(u.y)
                 + qh[4]*bu2f_lo(u.z) + qh[5]*bu2f_hi(u.z)
                 + qh[6]*bu2f_lo(u.w) + qh[7]*bu2f_hi(u.w);
        }
        float sc = fminf(scale[h], 100.f);
        s[idx] = acc*sc + p[(size_t)rel_idx[n*NTOK+m]*NHEAD + h];
    }
    __syncthreads();
    // premix over heads + adjacency mask
    for (int idx=tid; idx<NHEAD*NTOK; idx+=256){
        int o = idx/NTOK, m = idx - o*NTOK;
        float acc = 0.f;
        #pragma unroll
        for (int h=0;h<NHEAD;h++) acc += pre_w[o*NHEAD+h] * s[h*NTOK+m];
        bool on = prior_adj[((size_t)o*NTOK+n)*NTOK + m] > 0.f;
        s2[idx] = on ? acc : -1e9f;
    }
    __syncthreads();
    // softmax per output head (wave handles rows o, o+4)
    for (int o=wv; o<NHEAD; o+=4){
        float mx = -3e38f;
        for (int m=ln; m<NTOK; m+=64) mx = fmaxf(mx, s2[o*NTOK+m]);
        #pragma unroll
        for (int off=32; off; off>>=1) mx = fmaxf(mx, __shfl_xor(mx,off,64));
        float sum = 0.f;
        for (int m=ln; m<NTOK; m+=64){ float e = __expf(s2[o*NTOK+m]-mx); s2[o*NTOK+m]=e; sum+=e; }
        #pragma unroll
        for (int off=32; off; off>>=1) sum += __shfl_xor(sum,off,64);
        float inv = 1.f/sum;
        for (int m=ln; m<NTOK; m+=64) s2[o*NTOK+m] *= inv;
    }
    __syncthreads();
    // postmix over heads -> s
    for (int idx=tid; idx<NHEAD*NTOK; idx+=256){
        int o2 = idx/NTOK, m = idx - o2*NTOK;
        float acc = 0.f;
        #pragma unroll
        for (int o=0;o<NHEAD;o++) acc += post_w[o2*NHEAD+o] * s2[o*NTOK+m];
        s[idx] = acc;
    }
    __syncthreads();
    // @V : ao[b][n][h*96+di] = sum_m s[h][m] * v[b][h][m][di]
    for (int idx=tid; idx<DIMC; idx+=256){
        int h = idx/96, di = idx - h*96;
        const bf16* vbp = v + (((size_t)b*NHEAD+h)*NTOK)*DHEAD + di;
        const float* arow = s + h*NTOK;
        float acc = 0.f;
        for (int m=0;m<NTOK;m++) acc += arow[m]*b2f(vbp[(size_t)m*DHEAD]);
        ao[((size_t)b*NTOK+n)*DIMC + idx] = f2b(acc);
    }
}

// ---------------- MFMA GEMM: C = A(MxK,bf16) . B(NxK,f32->bf16)^T, 64x64 tile, BK=32 ----------------
enum { EPI_QKV=0, EPI_RES=1, EPI_GELU=2, EPI_ACC=3 };
constexpr int BM=64, BN=64, BK=32, LDSK=40;   // pad: 80B row stride (16B aligned, 2-way banks = free)

template<int EPI>
__global__ __launch_bounds__(256) void gemm_nt(
    const bf16* __restrict__ A, int lda,
    const float* __restrict__ B, int ldb,
    int K,
    const float* __restrict__ bias,
    const float* __restrict__ resid,    // RES: residual source (f32), stride DIMC
    float* __restrict__ dst_f,          // RES/ACC dest (f32), stride DIMC
    bf16* __restrict__ dst_b, int lddb, // GELU dest (bf16)
    bf16* __restrict__ qo, bf16* __restrict__ ko, bf16* __restrict__ vo)  // QKV dests
{
    __shared__ bf16 As[BM*LDSK];
    __shared__ bf16 Bs[BN*LDSK];
    const int tid = threadIdx.x;
    const int wv = tid >> 6, ln = tid & 63;
    const int fr = ln & 15, fq = ln >> 4;
    const int m0 = blockIdx.y*BM, n0 = blockIdx.x*BN;
    const int srow = tid >> 2, scol = (tid & 3)*8;
    const bf16*  Ag = A + (size_t)(m0+srow)*lda + scol;
    const float* Bg = B + (size_t)(n0+srow)*ldb + scol;
    f32x4 acc[4] = {};
    for (int k0=0; k0<K; k0+=BK){
        uint4  av = *reinterpret_cast<const uint4*>(Ag + k0);
        float4 b0 = *reinterpret_cast<const float4*>(Bg + k0);
        float4 b1 = *reinterpret_cast<const float4*>(Bg + k0 + 4);
        __syncthreads();
        *reinterpret_cast<uint4*>(&As[srow*LDSK + scol]) = av;
        bf16 tb[8];
        tb[0]=f2b(b0.x); tb[1]=f2b(b0.y); tb[2]=f2b(b0.z); tb[3]=f2b(b0.w);
        tb[4]=f2b(b1.x); tb[5]=f2b(b1.y); tb[6]=f2b(b1.z); tb[7]=f2b(b1.w);
        *reinterpret_cast<uint4*>(&Bs[srow*LDSK + scol]) = *reinterpret_cast<uint4*>(tb);
        __syncthreads();
        bf16x8 af = *reinterpret_cast<const bf16x8*>(&As[(wv*16+fr)*LDSK + fq*8]);
        #pragma unroll
        for (int c=0;c<4;c++){
            bf16x8 bfv = *reinterpret_cast<const bf16x8*>(&Bs[(c*16+fr)*LDSK + fq*8]);
            acc[c] = __builtin_amdgcn_mfma_f32_16x16x32_bf16(af, bfv, acc[c], 0, 0, 0);
        }
    }
    #pragma unroll
    for (int c=0;c<4;c++){
        #pragma unroll
        for (int i=0;i<4;i++){
            int row = m0 + wv*16 + fq*4 + i;    // C/D: row=(lane>>4)*4+reg, col=lane&15 (m89/m91)
            int col = n0 + c*16 + fr;
            float val = acc[c][i];
            if constexpr (EPI == EPI_QKV){
                int which = col/768, rem = col - which*768;
                int hh = rem/96, di = rem - hh*96;
                int bb = row/NTOK, nn = row - bb*NTOK;
                bf16* dst = (which==0) ? qo : ((which==1) ? ko : vo);
                dst[(((size_t)bb*NHEAD+hh)*NTOK+nn)*DHEAD + di] = f2b(val);
            } else if constexpr (EPI == EPI_RES){
                dst_f[(size_t)row*DIMC + col] = val + bias[col] + resid[(size_t)row*DIMC + col];
            } else if constexpr (EPI == EPI_GELU){
                float t = val + bias[col];
                t = 0.5f*t*(1.f + erff(t*0.70710678118654752f));
                dst_b[(size_t)row*lddb + col] = f2b(t);
            } else { // EPI_ACC
                dst_f[(size_t)row*DIMC + col] += val;
            }
        }
    }
}

extern "C" void kernel_launch(void* const* d_in, const int* in_sizes, int n_in,
                              void* d_out, int out_size, void* d_ws, size_t ws_size,
                              hipStream_t stream)
{
    const float* x        = (const float*)d_in[0];
    const float* norm1_w  = (const float*)d_in[1];
    const float* norm1_b  = (const float*)d_in[2];
    const float* qkv_w    = (const float*)d_in[3];
    const float* scale    = (const float*)d_in[4];
    const float* pp_w     = (const float*)d_in[5];
    const float* pp_b     = (const float*)d_in[6];
    const float* ln1_w    = (const float*)d_in[7];
    const float* ln1_b    = (const float*)d_in[8];
    const float* fcp1_w   = (const float*)d_in[9];
    const float* fcp1_b   = (const float*)d_in[10];
    const float* ln2_w    = (const float*)d_in[11];
    const float* ln2_b    = (const float*)d_in[12];
    const float* fcp2_w   = (const float*)d_in[13];
    const float* fcp2_b   = (const float*)d_in[14];
    const float* ln3_w    = (const float*)d_in[15];
    const float* ln3_b    = (const float*)d_in[16];
    const float* fcp3_w   = (const float*)d_in[17];
    const float* fcp3_b   = (const float*)d_in[18];
    const float* pre_w    = (const float*)d_in[19];
    const float* post_w   = (const float*)d_in[20];
    const float* proj_w   = (const float*)d_in[21];
    const float* proj_b   = (const float*)d_in[22];
    const float* nrm2_w   = (const float*)d_in[23];
    const float* nrm2_b   = (const float*)d_in[24];
    const float* m1_w     = (const float*)d_in[25];
    const float* m1_b     = (const float*)d_in[26];
    const float* m2_w     = (const float*)d_in[27];
    const float* m2_b     = (const float*)d_in[28];
    const float* prior    = (const float*)d_in[29];
    const float* biases   = (const float*)d_in[30];
    const int*   rel_idx  = (const int*)d_in[31];
    float* out = (float*)d_out;

    char* ws = (char*)d_ws;
    float* p   = (float*)(ws);
    bf16*  h   = (bf16*)(ws + OFF_H);     // LN1 out; later LN2 out
    bf16*  qb  = (bf16*)(ws + OFF_Q);
    bf16*  kb  = (bf16*)(ws + OFF_K);
    bf16*  vb  = (bf16*)(ws + OFF_V);
    bf16*  ao  = (bf16*)(ws + OFF_AO);
    float* x1  = (float*)(ws + OFF_Q);    // reuses q+k after attention (exactly 12608*768*4 B)
    bf16*  mid = (bf16*)(ws + OFF_V);     // reuses v+ao after proj (exactly 12608*1536*2 B)

    pos_mlp<<<841, 64, 0, stream>>>(biases, pp_w, pp_b, ln1_w, ln1_b, fcp1_w, fcp1_b,
                                    ln2_w, ln2_b, fcp2_w, fcp2_b, ln3_w, ln3_b, fcp3_w, fcp3_b, p);
    ln768<<<NROWS, 256, 0, stream>>>(x, norm1_w, norm1_b, h);
    gemm_nt<EPI_QKV><<<dim3(36, NROWS/64), 256, 0, stream>>>(
        h, DIMC, qkv_w, DIMC, DIMC, nullptr, nullptr, nullptr, nullptr, 0, qb, kb, vb);
    l2norm_qk<<<(NBATCH*NHEAD*NTOK*2)/4, 256, 0, stream>>>(qb, kb);
    attn_fused<<<dim3(NTOK, NBATCH), 256, 0, stream>>>(
        qb, kb, vb, p, rel_idx, prior, scale, pre_w, post_w, ao);
    gemm_nt<EPI_RES><<<dim3(12, NROWS/64), 256, 0, stream>>>(
        ao, DIMC, proj_w, DIMC, DIMC, proj_b, x, x1, nullptr, 0, nullptr, nullptr, nullptr);
    ln768<<<NROWS, 256, 0, stream>>>(x1, nrm2_w, nrm2_b, h);
    // MLP in two HID/2=1536 chunks (mid reuses v+ao region)
    for (int c=0; c<2; c++){
        gemm_nt<EPI_GELU><<<dim3(24, NROWS/64), 256, 0, stream>>>(
            h, DIMC, m1_w + (size_t)c*1536*DIMC, DIMC, DIMC, m1_b + c*1536,
            nullptr, nullptr, mid, 1536, nullptr, nullptr, nullptr);
        if (c == 0)
            gemm_nt<EPI_ACC><<<dim3(12, NROWS/64), 256, 0, stream>>>(
                mid, 1536, m2_w, 3072, 1536, nullptr, nullptr, x1, nullptr, 0,
                nullptr, nullptr, nullptr);
        else
            gemm_nt<EPI_RES><<<dim3(12, NROWS/64), 256, 0, stream>>>(
                mid, 1536, m2_w + 1536, 3072, 1536, m2_b, x1, out, nullptr, 0,
                nullptr, nullptr, nullptr);
    }
    (void)in_sizes; (void)n_in; (void)out_size; (void)ws_size;
}

// Round 3
// 1001.337 us; speedup vs baseline: 1.6088x; 1.6088x over previous
//
#include <hip/hip_runtime.h>
#include <hip/hip_bf16.h>
#include <math.h>

typedef __hip_bfloat16 bf16;
typedef __attribute__((ext_vector_type(8))) short bf16x8;   // 8 bf16 (4 VGPRs)
typedef __attribute__((ext_vector_type(4))) float f32x4;

__device__ __forceinline__ float b2f(bf16 x){ return __bfloat162float(x); }
__device__ __forceinline__ bf16  f2b(float x){ return __float2bfloat16(x); }

#define NTOK 197
#define NBATCH 64
#define NHEAD 8
#define DHEAD 96
#define DIMC 768
#define NROWS (NBATCH * NTOK)   // 12608
#define VTS 200                 // vt row stride (bf16 elems), 16B-aligned rows
#define SMS 228                 // LDS score row stride (floats): 228%32=4 -> <=2-way banks

// ---------------- workspace layout (bytes) ----------------
// p (841x8 f32)              @ 0        (32 KB reserved)
// h (12608x768 bf16)         @ OFF_H    -> after QKV: ao ; after proj: mid
// q (bf16)                   @ OFF_Q    -> after attn: x1 (f32 spans q+k)
// k (bf16)                   @ OFF_K
// vt (bf16, [b][h][96][VTS]) @ OFF_V    -> after attn: h2 (LN2 out)
#define OFF_H  32768ull
#define SZ_H   19365888ull
#define OFF_Q  (OFF_H + SZ_H)
#define OFF_K  (OFF_Q + SZ_H)
#define OFF_V  (OFF_K + SZ_H)
#define SZ_VT  19660800ull      // 64*8*96*200*2 ; end = 77,791,232 (< proven-safe 96.9MB)

// ---------------- position-bias MLP (841 rows, tiny, all f32) ----------------
__global__ __launch_bounds__(64) void pos_mlp(
    const float* __restrict__ biases, const float* __restrict__ pp_w, const float* __restrict__ pp_b,
    const float* __restrict__ ln1w, const float* __restrict__ ln1b,
    const float* __restrict__ f1w,  const float* __restrict__ f1b,
    const float* __restrict__ ln2w, const float* __restrict__ ln2b,
    const float* __restrict__ f2w,  const float* __restrict__ f2b,
    const float* __restrict__ ln3w, const float* __restrict__ ln3b,
    const float* __restrict__ f3w,  const float* __restrict__ f3b,
    float* __restrict__ pout)
{
    const int row = blockIdx.x, j = threadIdx.x;
    __shared__ float va[48], vb[48];
    float b0 = biases[row*2], b1 = biases[row*2+1];
    if (j < 48) va[j] = b0*pp_w[j*2] + b1*pp_w[j*2+1] + pp_b[j];
    __syncthreads();
    {   float s=0.f, s2=0.f;
        for (int i=0;i<48;i++){ float t=va[i]; s+=t; s2+=t*t; }
        float mean=s*(1.f/48.f), var=s2*(1.f/48.f)-mean*mean, inv=rsqrtf(var+1e-5f);
        float r=0.f;
        if (j < 48){
            r = f1b[j];
            for (int i=0;i<48;i++){
                float t = fmaxf((va[i]-mean)*inv*ln1w[i] + ln1b[i], 0.f);
                r += t * f1w[j*48+i];
            }
        }
        __syncthreads();
        if (j < 48) vb[j] = r;
    }
    __syncthreads();
    {   float s=0.f, s2=0.f;
        for (int i=0;i<48;i++){ float t=vb[i]; s+=t; s2+=t*t; }
        float mean=s*(1.f/48.f), var=s2*(1.f/48.f)-mean*mean, inv=rsqrtf(var+1e-5f);
        float r=0.f;
        if (j < 48){
            r = f2b[j];
            for (int i=0;i<48;i++){
                float t = fmaxf((vb[i]-mean)*inv*ln2w[i] + ln2b[i], 0.f);
                r += t * f2w[j*48+i];
            }
        }
        __syncthreads();
        if (j < 48) va[j] = r;
    }
    __syncthreads();
    {   float s=0.f, s2=0.f;
        for (int i=0;i<48;i++){ float t=va[i]; s+=t; s2+=t*t; }
        float mean=s*(1.f/48.f), var=s2*(1.f/48.f)-mean*mean, inv=rsqrtf(var+1e-5f);
        if (j < 8){
            float r = f3b[j];
            for (int i=0;i<48;i++){
                float t = fmaxf((va[i]-mean)*inv*ln3w[i] + ln3b[i], 0.f);
                r += t * f3w[j*48+i];
            }
            pout[row*8+j] = r;
        }
    }
}

// ---------------- LayerNorm over 768 (f32 in, bf16 out) ----------------
__global__ __launch_bounds__(256) void ln768(
    const float* __restrict__ x, const float* __restrict__ w, const float* __restrict__ b,
    bf16* __restrict__ out)
{
    const int row = blockIdx.x, tid = threadIdx.x;
    const int wv = tid >> 6, ln = tid & 63;
    __shared__ float rs[4], rs2[4];
    const float* xr = x + (size_t)row * DIMC;
    float v0 = xr[tid], v1 = xr[tid+256], v2 = xr[tid+512];
    float s = v0+v1+v2, s2 = v0*v0+v1*v1+v2*v2;
    #pragma unroll
    for (int off=32; off; off>>=1){ s += __shfl_xor(s,off,64); s2 += __shfl_xor(s2,off,64); }
    if (ln == 0){ rs[wv]=s; rs2[wv]=s2; }
    __syncthreads();
    s = rs[0]+rs[1]+rs[2]+rs[3]; s2 = rs2[0]+rs2[1]+rs2[2]+rs2[3];
    float mean = s*(1.f/768.f), var = s2*(1.f/768.f) - mean*mean;
    float inv = rsqrtf(var + 1e-5f);
    size_t base = (size_t)row * DIMC;
    out[base+tid]     = f2b((v0-mean)*inv*w[tid]     + b[tid]);
    out[base+tid+256] = f2b((v1-mean)*inv*w[tid+256] + b[tid+256]);
    out[base+tid+512] = f2b((v2-mean)*inv*w[tid+512] + b[tid+512]);
}

// ---------------- l2-normalize q,k rows (96 elems, bf16 in-place) ----------------
__global__ __launch_bounds__(256) void l2norm_qk(bf16* __restrict__ q, bf16* __restrict__ k)
{
    const int wv = threadIdx.x >> 6, ln = threadIdx.x & 63;
    const size_t NR = (size_t)NBATCH*NHEAD*NTOK;
    size_t row = (size_t)blockIdx.x * 4 + wv;
    bf16* ptr = (row < NR) ? (q + row*DHEAD) : (k + (row-NR)*DHEAD);
    float x0 = b2f(ptr[ln]);
    float x1 = (ln < 32) ? b2f(ptr[64+ln]) : 0.f;
    float ss = x0*x0 + x1*x1;
    #pragma unroll
    for (int off=32; off; off>>=1) ss += __shfl_xor(ss,off,64);
    float inv = 1.f / fmaxf(sqrtf(ss), 1e-12f);
    ptr[ln] = f2b(x0*inv);
    if (ln < 32) ptr[64+ln] = f2b(x1*inv);
}

// ---------------- MFMA attention: one block per (batch, 8-token q-tile) ----------------
__global__ __launch_bounds__(256) void attn_mfma(
    const bf16* __restrict__ q, const bf16* __restrict__ k, const bf16* __restrict__ vt,
    const float* __restrict__ p, const float* __restrict__ scale,
    const float* __restrict__ pre_w, const float* __restrict__ post_w,
    bf16* __restrict__ ao)
{
    const int b = blockIdx.y, n0 = blockIdx.x*8;
    const int tid = threadIdx.x, wv = tid>>6, ln = tid&63;
    const int fr = ln&15, fq = ln>>4;
    __shared__ float S[NHEAD*8*SMS];         // 58,368 B
    __shared__ float s_pre[64], s_post[64], s_sc[8];
    if (tid < 64){ s_pre[tid]=pre_w[tid]; s_post[tid]=post_w[tid]; }
    if (tid < 8)  s_sc[tid] = fminf(scale[tid], 100.f);

    // ---- stage 1: raw scores S[h][nq][m] = q.k  (wave handles heads wv, wv+4)
    #pragma unroll
    for (int hh=0; hh<2; hh++){
        const int h = wv + hh*4;
        int qr = n0 + fr; if (qr > 196) qr = 196;
        const bf16* qrow = q + ((size_t)(b*NHEAD+h)*NTOK + qr)*DHEAD + fq*8;
        bf16x8 a0 = *(const bf16x8*)(qrow);
        bf16x8 a1 = *(const bf16x8*)(qrow+32);
        bf16x8 a2 = *(const bf16x8*)(qrow+64);
        const bf16* kb0 = k + (size_t)(b*NHEAD+h)*NTOK*DHEAD + fq*8;
        for (int mt=0; mt<13; mt++){
            int mr = mt*16+fr; if (mr>196) mr=196;
            const bf16* kr = kb0 + (size_t)mr*DHEAD;
            f32x4 acc = {};
            acc = __builtin_amdgcn_mfma_f32_16x16x32_bf16(a0, *(const bf16x8*)(kr),    acc,0,0,0);
            acc = __builtin_amdgcn_mfma_f32_16x16x32_bf16(a1, *(const bf16x8*)(kr+32), acc,0,0,0);
            acc = __builtin_amdgcn_mfma_f32_16x16x32_bf16(a2, *(const bf16x8*)(kr+64), acc,0,0,0);
            if (fq < 2){            // rows nq = fq*4+i in [0,8)
                #pragma unroll
                for (int i=0;i<4;i++)
                    S[(h*8 + fq*4+i)*SMS + mt*16+fr] = acc[i];
            }
        }
    }
    __syncthreads();

    // ---- stage 2: scale + rel-pos bias + premix + geometric mask (per column, in place)
    const int sco[8] = {1,1,4,4,7,7,1000,1000};
    for (int c=tid; c<8*224; c+=256){
        int nq = c/224, m = c - nq*224;
        if (m >= 197){
            #pragma unroll
            for (int o=0;o<8;o++) S[(o*8+nq)*SMS+m] = -1e9f;
            continue;
        }
        int n = n0+nq; if (n > 196) n = 196;
        bool always = (n==0) || (m==0);
        int ri=0, ci=0, rj=0, cj=0;
        if (!always){
            ri=(n-1)/14; ci=(n-1)-ri*14;
            rj=(m-1)/14; cj=(m-1)-rj*14;
        }
        int dr = ri-rj; if (dr<0) dr=-dr;
        int dc = ci-cj; if (dc<0) dc=-dc;
        int idx = always ? 730 : (ri-rj+13)*27 + (ci-cj+13);
        const float* pv = p + idx*8;
        float sh[8];
        #pragma unroll
        for (int h=0;h<8;h++) sh[h] = S[(h*8+nq)*SMS+m]*s_sc[h] + pv[h];
        float ov[8];
        #pragma unroll
        for (int o=0;o<8;o++){
            float v=0.f;
            #pragma unroll
            for (int hh2=0;hh2<8;hh2++) v += s_pre[o*8+hh2]*sh[hh2];
            bool on = always || (dr<=sco[o] && dc<=sco[o]);
            ov[o] = on ? v : -1e9f;
        }
        #pragma unroll
        for (int o=0;o<8;o++) S[(o*8+nq)*SMS+m] = ov[o];
    }
    __syncthreads();

    // ---- stage 3: softmax per (o,nq) row — 64 rows, 16 per wave
    for (int r = wv*16; r < wv*16+16; r++){
        float* row = &S[r*SMS];
        float mx = -3e38f;
        for (int m=ln; m<224; m+=64) mx = fmaxf(mx, row[m]);
        #pragma unroll
        for (int off=32; off; off>>=1) mx = fmaxf(mx, __shfl_xor(mx,off,64));
        float sum = 0.f;
        for (int m=ln; m<224; m+=64){ float e=__expf(row[m]-mx); row[m]=e; sum+=e; }
        #pragma unroll
        for (int off=32; off; off>>=1) sum += __shfl_xor(sum,off,64);
        float inv = 1.f/sum;
        for (int m=ln; m<224; m+=64) row[m] *= inv;
    }
    __syncthreads();

    // ---- stage 3.5: postmix over heads (per column, in place; m>=197 stay ~0)
    for (int c=tid; c<8*197; c+=256){
        int nq = c/197, m = c - nq*197;
        float ph[8];
        #pragma unroll
        for (int o=0;o<8;o++) ph[o] = S[(o*8+nq)*SMS+m];
        float ov[8];
        #pragma unroll
        for (int o2=0;o2<8;o2++){
            float v=0.f;
            #pragma unroll
            for (int o=0;o<8;o++) v += s_post[o2*8+o]*ph[o];
            ov[o2]=v;
        }
        #pragma unroll
        for (int o=0;o<8;o++) S[(o*8+nq)*SMS+m] = ov[o];
    }
    __syncthreads();

    // ---- stage 4: P @ V via MFMA (A rows 8..15 duplicate 0..7; their outputs discarded)
    const int frA = fr & 7;
    #pragma unroll
    for (int hh=0; hh<2; hh++){
        const int h = wv + hh*4;
        const bf16* vbase = vt + (size_t)(b*NHEAD+h)*DHEAD*VTS;
        for (int dt=0; dt<6; dt++){
            f32x4 acc = {};
            #pragma unroll
            for (int ks=0; ks<7; ks++){
                const float* ap = &S[(h*8+frA)*SMS + ks*32 + fq*8];
                f32x4 p0 = *(const f32x4*)ap;
                f32x4 p1 = *(const f32x4*)(ap+4);
                alignas(16) bf16 af[8] = { f2b(p0[0]),f2b(p0[1]),f2b(p0[2]),f2b(p0[3]),
                                           f2b(p1[0]),f2b(p1[1]),f2b(p1[2]),f2b(p1[3]) };
                const bf16* bp = vbase + (size_t)(dt*16+fr)*VTS + ks*32 + fq*8;
                acc = __builtin_amdgcn_mfma_f32_16x16x32_bf16(*(const bf16x8*)af, *(const bf16x8*)bp, acc,0,0,0);
            }
            #pragma unroll
            for (int i=0;i<4;i++){
                int nq = fq*4+i, n = n0+nq;
                if (nq < 8 && n < NTOK)
                    ao[((size_t)b*NTOK+n)*DIMC + h*DHEAD + dt*16+fr] = f2b(acc[i]);
            }
        }
    }
}

// ---------------- MFMA GEMM: C = A(MxK,bf16) . B(NxK,f32->bf16)^T, 64x64 tile ----------------
enum { EPI_QKV=0, EPI_RES=1, EPI_GELU=2, EPI_ACC=3 };
constexpr int BM=64, BN=64, BK=32, LDSK=40;

template<int EPI>
__global__ __launch_bounds__(256) void gemm_nt(
    const bf16* __restrict__ A, int lda,
    const float* __restrict__ B, int ldb,
    int K,
    const float* __restrict__ bias,
    const float* __restrict__ resid,
    float* __restrict__ dst_f,
    bf16* __restrict__ dst_b, int lddb,
    bf16* __restrict__ qo, bf16* __restrict__ ko, bf16* __restrict__ vto)
{
    __shared__ bf16 As[BM*LDSK];
    __shared__ bf16 Bs[BN*LDSK];
    const int tid = threadIdx.x;
    const int wv = tid >> 6, ln = tid & 63;
    const int fr = ln & 15, fq = ln >> 4;
    const int m0 = blockIdx.y*BM, n0 = blockIdx.x*BN;
    const int srow = tid >> 2, scol = (tid & 3)*8;
    const bf16*  Ag = A + (size_t)(m0+srow)*lda + scol;
    const float* Bg = B + (size_t)(n0+srow)*ldb + scol;
    f32x4 acc[4] = {};
    for (int k0=0; k0<K; k0+=BK){
        uint4  av = *reinterpret_cast<const uint4*>(Ag + k0);
        float4 b0 = *reinterpret_cast<const float4*>(Bg + k0);
        float4 b1 = *reinterpret_cast<const float4*>(Bg + k0 + 4);
        __syncthreads();
        *reinterpret_cast<uint4*>(&As[srow*LDSK + scol]) = av;
        bf16 tb[8];
        tb[0]=f2b(b0.x); tb[1]=f2b(b0.y); tb[2]=f2b(b0.z); tb[3]=f2b(b0.w);
        tb[4]=f2b(b1.x); tb[5]=f2b(b1.y); tb[6]=f2b(b1.z); tb[7]=f2b(b1.w);
        *reinterpret_cast<uint4*>(&Bs[srow*LDSK + scol]) = *reinterpret_cast<uint4*>(tb);
        __syncthreads();
        bf16x8 af = *reinterpret_cast<const bf16x8*>(&As[(wv*16+fr)*LDSK + fq*8]);
        #pragma unroll
        for (int c=0;c<4;c++){
            bf16x8 bfv = *reinterpret_cast<const bf16x8*>(&Bs[(c*16+fr)*LDSK + fq*8]);
            acc[c] = __builtin_amdgcn_mfma_f32_16x16x32_bf16(af, bfv, acc[c], 0, 0, 0);
        }
    }
    #pragma unroll
    for (int c=0;c<4;c++){
        #pragma unroll
        for (int i=0;i<4;i++){
            int row = m0 + wv*16 + fq*4 + i;
            int col = n0 + c*16 + fr;
            float val = acc[c][i];
            if constexpr (EPI == EPI_QKV){
                int which = col/768, rem = col - which*768;
                int hh = rem/96, di = rem - hh*96;
                int bb = row/NTOK, nn = row - bb*NTOK;
                if (which == 0)      qo[(((size_t)bb*NHEAD+hh)*NTOK+nn)*DHEAD + di] = f2b(val);
                else if (which == 1) ko[(((size_t)bb*NHEAD+hh)*NTOK+nn)*DHEAD + di] = f2b(val);
                else                 vto[(((size_t)bb*NHEAD+hh)*DHEAD+di)*VTS + nn] = f2b(val);
            } else if constexpr (EPI == EPI_RES){
                dst_f[(size_t)row*DIMC + col] = val + bias[col] + resid[(size_t)row*DIMC + col];
            } else if constexpr (EPI == EPI_GELU){
                float t = val + bias[col];
                t = 0.5f*t*(1.f + erff(t*0.70710678118654752f));
                dst_b[(size_t)row*lddb + col] = f2b(t);
            } else {
                dst_f[(size_t)row*DIMC + col] += val;
            }
        }
    }
}

extern "C" void kernel_launch(void* const* d_in, const int* in_sizes, int n_in,
                              void* d_out, int out_size, void* d_ws, size_t ws_size,
                              hipStream_t stream)
{
    const float* x        = (const float*)d_in[0];
    const float* norm1_w  = (const float*)d_in[1];
    const float* norm1_b  = (const float*)d_in[2];
    const float* qkv_w    = (const float*)d_in[3];
    const float* scale    = (const float*)d_in[4];
    const float* pp_w     = (const float*)d_in[5];
    const float* pp_b     = (const float*)d_in[6];
    const float* ln1_w    = (const float*)d_in[7];
    const float* ln1_b    = (const float*)d_in[8];
    const float* fcp1_w   = (const float*)d_in[9];
    const float* fcp1_b   = (const float*)d_in[10];
    const float* ln2_w    = (const float*)d_in[11];
    const float* ln2_b    = (const float*)d_in[12];
    const float* fcp2_w   = (const float*)d_in[13];
    const float* fcp2_b   = (const float*)d_in[14];
    const float* ln3_w    = (const float*)d_in[15];
    const float* ln3_b    = (const float*)d_in[16];
    const float* fcp3_w   = (const float*)d_in[17];
    const float* fcp3_b   = (const float*)d_in[18];
    const float* pre_w    = (const float*)d_in[19];
    const float* post_w   = (const float*)d_in[20];
    const float* proj_w   = (const float*)d_in[21];
    const float* proj_b   = (const float*)d_in[22];
    const float* nrm2_w   = (const float*)d_in[23];
    const float* nrm2_b   = (const float*)d_in[24];
    const float* m1_w     = (const float*)d_in[25];
    const float* m1_b     = (const float*)d_in[26];
    const float* m2_w     = (const float*)d_in[27];
    const float* m2_b     = (const float*)d_in[28];
    const float* biases   = (const float*)d_in[30];
    float* out = (float*)d_out;

    char* ws = (char*)d_ws;
    float* p   = (float*)(ws);
    bf16*  h   = (bf16*)(ws + OFF_H);
    bf16*  qb  = (bf16*)(ws + OFF_Q);
    bf16*  kb  = (bf16*)(ws + OFF_K);
    bf16*  vt  = (bf16*)(ws + OFF_V);
    bf16*  ao  = (bf16*)(ws + OFF_H);
    float* x1  = (float*)(ws + OFF_Q);
    bf16*  h2  = (bf16*)(ws + OFF_V);
    bf16*  mid = (bf16*)(ws + OFF_H);

    pos_mlp<<<841, 64, 0, stream>>>(biases, pp_w, pp_b, ln1_w, ln1_b, fcp1_w, fcp1_b,
                                    ln2_w, ln2_b, fcp2_w, fcp2_b, ln3_w, ln3_b, fcp3_w, fcp3_b, p);
    ln768<<<NROWS, 256, 0, stream>>>(x, norm1_w, norm1_b, h);
    gemm_nt<EPI_QKV><<<dim3(36, NROWS/64), 256, 0, stream>>>(
        h, DIMC, qkv_w, DIMC, DIMC, nullptr, nullptr, nullptr, nullptr, 0, qb, kb, vt);
    l2norm_qk<<<(NBATCH*NHEAD*NTOK*2)/4, 256, 0, stream>>>(qb, kb);
    attn_mfma<<<dim3(25, NBATCH), 256, 0, stream>>>(qb, kb, vt, p, scale, pre_w, post_w, ao);
    gemm_nt<EPI_RES><<<dim3(12, NROWS/64), 256, 0, stream>>>(
        ao, DIMC, proj_w, DIMC, DIMC, proj_b, x, x1, nullptr, 0, nullptr, nullptr, nullptr);
    ln768<<<NROWS, 256, 0, stream>>>(x1, nrm2_w, nrm2_b, h2);
    for (int c=0; c<4; c++){
        gemm_nt<EPI_GELU><<<dim3(12, NROWS/64), 256, 0, stream>>>(
            h2, DIMC, m1_w + (size_t)c*768*DIMC, DIMC, DIMC, m1_b + c*768,
            nullptr, nullptr, mid, 768, nullptr, nullptr, nullptr);
        if (c < 3)
            gemm_nt<EPI_ACC><<<dim3(12, NROWS/64), 256, 0, stream>>>(
                mid, 768, m2_w + c*768, 3072, 768, nullptr, nullptr, x1, nullptr, 0,
                nullptr, nullptr, nullptr);
        else
            gemm_nt<EPI_RES><<<dim3(12, NROWS/64), 256, 0, stream>>>(
                mid, 768, m2_w + c*768, 3072, 768, m2_b, x1, out, nullptr, 0,
                nullptr, nullptr, nullptr);
    }
    (void)in_sizes; (void)n_in; (void)out_size; (void)ws_size;
}

// Round 4
// 927.483 us; speedup vs baseline: 1.7369x; 1.0796x over previous
//
#include <hip/hip_runtime.h>
#include <hip/hip_bf16.h>
#include <math.h>

typedef __hip_bfloat16 bf16;
typedef __attribute__((ext_vector_type(8))) short bf16x8;   // 8 bf16 (4 VGPRs)
typedef __attribute__((ext_vector_type(4))) float f32x4;

__device__ __forceinline__ float b2f(bf16 x){ return __bfloat162float(x); }
__device__ __forceinline__ bf16  f2b(float x){ return __float2bfloat16(x); }

// async global->LDS 16B (m97 pattern): LDS dest = wave-uniform base + lane*16
__device__ __forceinline__ void gld16(const bf16* g, bf16* l){
    __builtin_amdgcn_global_load_lds(
        (const __attribute__((address_space(1))) unsigned int*)g,
        (__attribute__((address_space(3))) unsigned int*)l, 16, 0, 0);
}

#define NTOK 197
#define NBATCH 64
#define NHEAD 8
#define DHEAD 96
#define DIMC 768
#define NROWS (NBATCH * NTOK)   // 12608
#define VTS 200                 // vt row stride (bf16)
#define SMS 228                 // LDS score row stride (f32)

// ---------------- workspace layout (bytes) ----------------
#define OFF_P   0ull
#define OFF_W   32768ull
#define SZ_QKVW 3538944ull      // 2304*768*2
#define SZ_PRJW 1179648ull      // 768*768*2
#define SZ_M1W  4718592ull      // 3072*768*2
#define SZ_M2W  4718592ull      // 768*3072*2
#define OFF_H   (OFF_W + SZ_QKVW + SZ_PRJW + SZ_M1W + SZ_M2W)   // 14,188,544
#define SZ_H    19365888ull     // 12608*768*2
#define OFF_Q   (OFF_H + SZ_H)
#define OFF_K   (OFF_Q + SZ_H)
#define OFF_V   (OFF_K + SZ_H)  // vt: 64*8*96*200*2 = 19,660,800 ; end ~92.0 MB (< proven 96.9)

// ---------------- f32 -> bf16 weight convert ----------------
__global__ __launch_bounds__(256) void w_cvt(const float* __restrict__ s, bf16* __restrict__ d, int n4){
    int i = blockIdx.x*256 + threadIdx.x;
    if (i < n4){
        float4 v = ((const float4*)s)[i];
        bf16 t[4] = {f2b(v.x), f2b(v.y), f2b(v.z), f2b(v.w)};
        ((ushort4*)d)[i] = *(ushort4*)t;
    }
}

// ---------------- position-bias MLP (841 rows, tiny, all f32) ----------------
__global__ __launch_bounds__(64) void pos_mlp(
    const float* __restrict__ biases, const float* __restrict__ pp_w, const float* __restrict__ pp_b,
    const float* __restrict__ ln1w, const float* __restrict__ ln1b,
    const float* __restrict__ f1w,  const float* __restrict__ f1b,
    const float* __restrict__ ln2w, const float* __restrict__ ln2b,
    const float* __restrict__ f2w,  const float* __restrict__ f2b,
    const float* __restrict__ ln3w, const float* __restrict__ ln3b,
    const float* __restrict__ f3w,  const float* __restrict__ f3b,
    float* __restrict__ pout)
{
    const int row = blockIdx.x, j = threadIdx.x;
    __shared__ float va[48], vb[48];
    float b0 = biases[row*2], b1 = biases[row*2+1];
    if (j < 48) va[j] = b0*pp_w[j*2] + b1*pp_w[j*2+1] + pp_b[j];
    __syncthreads();
    {   float s=0.f, s2=0.f;
        for (int i=0;i<48;i++){ float t=va[i]; s+=t; s2+=t*t; }
        float mean=s*(1.f/48.f), var=s2*(1.f/48.f)-mean*mean, inv=rsqrtf(var+1e-5f);
        float r=0.f;
        if (j < 48){
            r = f1b[j];
            for (int i=0;i<48;i++){
                float t = fmaxf((va[i]-mean)*inv*ln1w[i] + ln1b[i], 0.f);
                r += t * f1w[j*48+i];
            }
        }
        __syncthreads();
        if (j < 48) vb[j] = r;
    }
    __syncthreads();
    {   float s=0.f, s2=0.f;
        for (int i=0;i<48;i++){ float t=vb[i]; s+=t; s2+=t*t; }
        float mean=s*(1.f/48.f), var=s2*(1.f/48.f)-mean*mean, inv=rsqrtf(var+1e-5f);
        float r=0.f;
        if (j < 48){
            r = f2b[j];
            for (int i=0;i<48;i++){
                float t = fmaxf((vb[i]-mean)*inv*ln2w[i] + ln2b[i], 0.f);
                r += t * f2w[j*48+i];
            }
        }
        __syncthreads();
        if (j < 48) va[j] = r;
    }
    __syncthreads();
    {   float s=0.f, s2=0.f;
        for (int i=0;i<48;i++){ float t=va[i]; s+=t; s2+=t*t; }
        float mean=s*(1.f/48.f), var=s2*(1.f/48.f)-mean*mean, inv=rsqrtf(var+1e-5f);
        if (j < 8){
            float r = f3b[j];
            for (int i=0;i<48;i++){
                float t = fmaxf((va[i]-mean)*inv*ln3w[i] + ln3b[i], 0.f);
                r += t * f3w[j*48+i];
            }
            pout[row*8+j] = r;
        }
    }
}

// ---------------- LayerNorm over 768 (f32 in, bf16 out) ----------------
__global__ __launch_bounds__(256) void ln768(
    const float* __restrict__ x, const float* __restrict__ w, const float* __restrict__ b,
    bf16* __restrict__ out)
{
    const int row = blockIdx.x, tid = threadIdx.x;
    const int wv = tid >> 6, ln = tid & 63;
    __shared__ float rs[4], rs2[4];
    const float* xr = x + (size_t)row * DIMC;
    float v0 = xr[tid], v1 = xr[tid+256], v2 = xr[tid+512];
    float s = v0+v1+v2, s2 = v0*v0+v1*v1+v2*v2;
    #pragma unroll
    for (int off=32; off; off>>=1){ s += __shfl_xor(s,off,64); s2 += __shfl_xor(s2,off,64); }
    if (ln == 0){ rs[wv]=s; rs2[wv]=s2; }
    __syncthreads();
    s = rs[0]+rs[1]+rs[2]+rs[3]; s2 = rs2[0]+rs2[1]+rs2[2]+rs2[3];
    float mean = s*(1.f/768.f), var = s2*(1.f/768.f) - mean*mean;
    float inv = rsqrtf(var + 1e-5f);
    size_t base = (size_t)row * DIMC;
    out[base+tid]     = f2b((v0-mean)*inv*w[tid]     + b[tid]);
    out[base+tid+256] = f2b((v1-mean)*inv*w[tid+256] + b[tid+256]);
    out[base+tid+512] = f2b((v2-mean)*inv*w[tid+512] + b[tid+512]);
}

// ---------------- l2-normalize q,k rows (96 elems, bf16 in-place) ----------------
__global__ __launch_bounds__(256) void l2norm_qk(bf16* __restrict__ q, bf16* __restrict__ k)
{
    const int wv = threadIdx.x >> 6, ln = threadIdx.x & 63;
    const size_t NR = (size_t)NBATCH*NHEAD*NTOK;
    size_t row = (size_t)blockIdx.x * 4 + wv;
    bf16* ptr = (row < NR) ? (q + row*DHEAD) : (k + (row-NR)*DHEAD);
    float x0 = b2f(ptr[ln]);
    float x1 = (ln < 32) ? b2f(ptr[64+ln]) : 0.f;
    float ss = x0*x0 + x1*x1;
    #pragma unroll
    for (int off=32; off; off>>=1) ss += __shfl_xor(ss,off,64);
    float inv = 1.f / fmaxf(sqrtf(ss), 1e-12f);
    ptr[ln] = f2b(x0*inv);
    if (ln < 32) ptr[64+ln] = f2b(x1*inv);
}

// ---------------- MFMA attention: XCD-swizzled 1D grid, (batch, 8-token q-tile) ----------------
__global__ __launch_bounds__(256) void attn_mfma(
    const bf16* __restrict__ q, const bf16* __restrict__ k, const bf16* __restrict__ vt,
    const float* __restrict__ p, const float* __restrict__ scale,
    const float* __restrict__ pre_w, const float* __restrict__ post_w,
    bf16* __restrict__ ao)
{
    // swizzle: batch b's 25 blocks share id%8 == b%8 (same XCD under round-robin heuristic)
    const int id = blockIdx.x;
    const int r8 = id & 7, t8 = id >> 3;
    const int bx = t8 % 25, b = r8 + 8*(t8/25);
    const int n0 = bx*8;
    const int tid = threadIdx.x, wv = tid>>6, ln = tid&63;
    const int fr = ln&15, fq = ln>>4;
    __shared__ float S[NHEAD*8*SMS];         // 58,368 B ; aliased as bf16 Sb (stride 456) after postmix
    __shared__ float s_pre[64], s_post[64], s_sc[8];
    bf16* Sb = (bf16*)S;
    if (tid < 64){ s_pre[tid]=pre_w[tid]; s_post[tid]=post_w[tid]; }
    if (tid < 8)  s_sc[tid] = fminf(scale[tid], 100.f);

    // ---- stage 1: raw scores S[h][nq][m] = q.k (wave: heads wv, wv+4) with k prefetch
    #pragma unroll
    for (int hh=0; hh<2; hh++){
        const int h = wv + hh*4;
        int qr = n0 + fr; if (qr > 196) qr = 196;
        const bf16* qrow = q + ((size_t)(b*NHEAD+h)*NTOK + qr)*DHEAD + fq*8;
        bf16x8 a0 = *(const bf16x8*)(qrow);
        bf16x8 a1 = *(const bf16x8*)(qrow+32);
        bf16x8 a2 = *(const bf16x8*)(qrow+64);
        const bf16* kb0 = k + (size_t)(b*NHEAD+h)*NTOK*DHEAD + fq*8;
        int mr0 = fr;
        const bf16* kr = kb0 + (size_t)mr0*DHEAD;
        bf16x8 kv0 = *(const bf16x8*)(kr);
        bf16x8 kv1 = *(const bf16x8*)(kr+32);
        bf16x8 kv2 = *(const bf16x8*)(kr+64);
        for (int mt=0; mt<13; mt++){
            bf16x8 c0=kv0, c1=kv1, c2=kv2;
            if (mt < 12){
                int nr = (mt+1)*16+fr; if (nr>196) nr=196;
                const bf16* kn = kb0 + (size_t)nr*DHEAD;
                kv0 = *(const bf16x8*)(kn);
                kv1 = *(const bf16x8*)(kn+32);
                kv2 = *(const bf16x8*)(kn+64);
            }
            f32x4 acc = {};
            acc = __builtin_amdgcn_mfma_f32_16x16x32_bf16(a0, c0, acc,0,0,0);
            acc = __builtin_amdgcn_mfma_f32_16x16x32_bf16(a1, c1, acc,0,0,0);
            acc = __builtin_amdgcn_mfma_f32_16x16x32_bf16(a2, c2, acc,0,0,0);
            if (fq < 2){
                #pragma unroll
                for (int i=0;i<4;i++)
                    S[(h*8 + fq*4+i)*SMS + mt*16+fr] = acc[i];
            }
        }
    }
    __syncthreads();

    // ---- stage 2: scale + rel-pos bias + premix + geometric mask
    const int sco[8] = {1,1,4,4,7,7,1000,1000};
    for (int c=tid; c<8*224; c+=256){
        int nq = c/224, m = c - nq*224;
        if (m >= 197){
            #pragma unroll
            for (int o=0;o<8;o++) S[(o*8+nq)*SMS+m] = -1e9f;
            continue;
        }
        int n = n0+nq; if (n > 196) n = 196;
        bool always = (n==0) || (m==0);
        int ri=0, ci=0, rj=0, cj=0;
        if (!always){
            ri=(n-1)/14; ci=(n-1)-ri*14;
            rj=(m-1)/14; cj=(m-1)-rj*14;
        }
        int dr = ri-rj; if (dr<0) dr=-dr;
        int dc = ci-cj; if (dc<0) dc=-dc;
        int idx = always ? 730 : (ri-rj+13)*27 + (ci-cj+13);
        const float* pv = p + idx*8;
        float sh[8];
        #pragma unroll
        for (int h=0;h<8;h++) sh[h] = S[(h*8+nq)*SMS+m]*s_sc[h] + pv[h];
        float ov[8];
        #pragma unroll
        for (int o=0;o<8;o++){
            float v=0.f;
            #pragma unroll
            for (int hh2=0;hh2<8;hh2++) v += s_pre[o*8+hh2]*sh[hh2];
            bool on = always || (dr<=sco[o] && dc<=sco[o]);
            ov[o] = on ? v : -1e9f;
        }
        #pragma unroll
        for (int o=0;o<8;o++) S[(o*8+nq)*SMS+m] = ov[o];
    }
    __syncthreads();

    // ---- stage 3: softmax per (o,nq) row — 64 rows, 16 per wave
    for (int r = wv*16; r < wv*16+16; r++){
        float* row = &S[r*SMS];
        float mx = -3e38f;
        for (int m=ln; m<224; m+=64) mx = fmaxf(mx, row[m]);
        #pragma unroll
        for (int off=32; off; off>>=1) mx = fmaxf(mx, __shfl_xor(mx,off,64));
        float sum = 0.f;
        for (int m=ln; m<224; m+=64){ float e=__expf(row[m]-mx); row[m]=e; sum+=e; }
        #pragma unroll
        for (int off=32; off; off>>=1) sum += __shfl_xor(sum,off,64);
        float inv = 1.f/sum;
        for (int m=ln; m<224; m+=64) row[m] *= inv;
    }
    __syncthreads();

    // ---- stage 3.5: postmix -> registers -> barrier -> bf16 in place (Sb stride 456)
    float ov[7][8];
    #pragma unroll
    for (int kk=0; kk<7; kk++){
        int c = tid + kk*256;
        if (c < 8*197){
            int nq = c/197, m = c - nq*197;
            float ph[8];
            #pragma unroll
            for (int o=0;o<8;o++) ph[o] = S[(o*8+nq)*SMS+m];
            #pragma unroll
            for (int o2=0;o2<8;o2++){
                float v=0.f;
                #pragma unroll
                for (int o=0;o<8;o++) v += s_post[o2*8+o]*ph[o];
                ov[kk][o2]=v;
            }
        }
    }
    __syncthreads();
    #pragma unroll
    for (int kk=0; kk<7; kk++){
        int c = tid + kk*256;
        if (c < 8*197){
            int nq = c/197, m = c - nq*197;
            #pragma unroll
            for (int o=0;o<8;o++) Sb[(o*8+nq)*456 + m] = f2b(ov[kk][o]);
        }
    }
    for (int i=tid; i<64*32; i+=256){    // zero pad cols 197..223
        int r = i>>5, mm = 197 + (i&31);
        if (mm < 224) Sb[r*456+mm] = f2b(0.f);
    }
    __syncthreads();

    // ---- stage 4: P @ V via MFMA, bf16 A frags straight from LDS
    const int frA = fr & 7;
    #pragma unroll
    for (int hh=0; hh<2; hh++){
        const int h = wv + hh*4;
        const bf16* vbase = vt + (size_t)(b*NHEAD+h)*DHEAD*VTS;
        for (int dt=0; dt<6; dt++){
            f32x4 acc = {};
            #pragma unroll
            for (int ks=0; ks<7; ks++){
                const bf16* ap = Sb + (h*8+frA)*456 + ks*32 + fq*8;
                const bf16* bp = vbase + (size_t)(dt*16+fr)*VTS + ks*32 + fq*8;
                acc = __builtin_amdgcn_mfma_f32_16x16x32_bf16(*(const bf16x8*)ap, *(const bf16x8*)bp, acc,0,0,0);
            }
            #pragma unroll
            for (int i=0;i<4;i++){
                int nq = fq*4+i, n = n0+nq;
                if (nq < 8 && n < NTOK)
                    ao[((size_t)b*NTOK+n)*DIMC + h*DHEAD + dt*16+fr] = f2b(acc[i]);
            }
        }
    }
}

// ---------------- m97-style MFMA GEMM: 128x128 tile, BK=32, global_load_lds ----------------
enum { EPI_QKV=0, EPI_RES=1, EPI_GELU=2, EPI_ACC=3 };

template<int EPI>
__global__ __launch_bounds__(256) void gemm128(
    const bf16* __restrict__ A, int lda, int M,
    const bf16* __restrict__ B, int ldb,
    int K,
    const float* __restrict__ bias,
    const float* __restrict__ resid,
    float* __restrict__ dst_f,
    bf16* __restrict__ dst_b, int lddb,
    bf16* __restrict__ qo, bf16* __restrict__ ko, bf16* __restrict__ vto)
{
    __shared__ bf16 As[128*32];
    __shared__ bf16 Bs[128*32];
    const int tid = threadIdx.x;
    const int wv = tid >> 6, ln = tid & 63;
    const int fr = ln & 15, fq = ln >> 4;
    const int wr = (wv & 1)*64, wc = (wv >> 1)*64;
    const int m0 = blockIdx.y*128, n0 = blockIdx.x*128;
    const int lnrow = ln >> 2, lncol = (ln & 3)*8;
    f32x4 acc[4][4] = {};
    for (int k0=0; k0<K; k0+=32){
        #pragma unroll
        for (int c=0;c<2;c++){
            int rA = m0 + (c*4+wv)*16 + lnrow;
            if (rA >= M) rA = M-1;
            gld16(A + (size_t)rA*lda + k0 + lncol, &As[(c*4+wv)*16*32]);
            int rB = n0 + (c*4+wv)*16 + lnrow;
            gld16(B + (size_t)rB*ldb + k0 + lncol, &Bs[(c*4+wv)*16*32]);
        }
        __syncthreads();
        bf16x8 af[4], bfv[4];
        #pragma unroll
        for (int i=0;i<4;i++){
            af[i]  = *(const bf16x8*)&As[(wr + i*16 + fr)*32 + fq*8];
            bfv[i] = *(const bf16x8*)&Bs[(wc + i*16 + fr)*32 + fq*8];
        }
        #pragma unroll
        for (int mi=0;mi<4;mi++)
            #pragma unroll
            for (int ni=0;ni<4;ni++)
                acc[mi][ni] = __builtin_amdgcn_mfma_f32_16x16x32_bf16(af[mi], bfv[ni], acc[mi][ni],0,0,0);
        __syncthreads();
    }
    #pragma unroll
    for (int mi=0;mi<4;mi++){
        #pragma unroll
        for (int ni=0;ni<4;ni++){
            #pragma unroll
            for (int i=0;i<4;i++){
                int row = m0 + wr + mi*16 + fq*4 + i;
                int col = n0 + wc + ni*16 + fr;
                if (row >= M) continue;
                float val = acc[mi][ni][i];
                if constexpr (EPI == EPI_QKV){
                    int which = col/768, rem = col - which*768;
                    int hh = rem/96, di = rem - hh*96;
                    int bb = row/NTOK, nn = row - bb*NTOK;
                    if (which == 0)      qo[(((size_t)bb*NHEAD+hh)*NTOK+nn)*DHEAD + di] = f2b(val);
                    else if (which == 1) ko[(((size_t)bb*NHEAD+hh)*NTOK+nn)*DHEAD + di] = f2b(val);
                    else                 vto[(((size_t)bb*NHEAD+hh)*DHEAD+di)*VTS + nn] = f2b(val);
                } else if constexpr (EPI == EPI_RES){
                    dst_f[(size_t)row*DIMC + col] = val + bias[col] + resid[(size_t)row*DIMC + col];
                } else if constexpr (EPI == EPI_GELU){
                    float t = val + bias[col];
                    t = 0.5f*t*(1.f + erff(t*0.70710678118654752f));
                    dst_b[(size_t)row*lddb + col] = f2b(t);
                } else {
                    dst_f[(size_t)row*DIMC + col] += val;
                }
            }
        }
    }
}

extern "C" void kernel_launch(void* const* d_in, const int* in_sizes, int n_in,
                              void* d_out, int out_size, void* d_ws, size_t ws_size,
                              hipStream_t stream)
{
    const float* x        = (const float*)d_in[0];
    const float* norm1_w  = (const float*)d_in[1];
    const float* norm1_b  = (const float*)d_in[2];
    const float* qkv_w    = (const float*)d_in[3];
    const float* scale    = (const float*)d_in[4];
    const float* pp_w     = (const float*)d_in[5];
    const float* pp_b     = (const float*)d_in[6];
    const float* ln1_w    = (const float*)d_in[7];
    const float* ln1_b    = (const float*)d_in[8];
    const float* fcp1_w   = (const float*)d_in[9];
    const float* fcp1_b   = (const float*)d_in[10];
    const float* ln2_w    = (const float*)d_in[11];
    const float* ln2_b    = (const float*)d_in[12];
    const float* fcp2_w   = (const float*)d_in[13];
    const float* fcp2_b   = (const float*)d_in[14];
    const float* ln3_w    = (const float*)d_in[15];
    const float* ln3_b    = (const float*)d_in[16];
    const float* fcp3_w   = (const float*)d_in[17];
    const float* fcp3_b   = (const float*)d_in[18];
    const float* pre_w    = (const float*)d_in[19];
    const float* post_w   = (const float*)d_in[20];
    const float* proj_w   = (const float*)d_in[21];
    const float* proj_b   = (const float*)d_in[22];
    const float* nrm2_w   = (const float*)d_in[23];
    const float* nrm2_b   = (const float*)d_in[24];
    const float* m1_w     = (const float*)d_in[25];
    const float* m1_b     = (const float*)d_in[26];
    const float* m2_w     = (const float*)d_in[27];
    const float* m2_b     = (const float*)d_in[28];
    const float* biases   = (const float*)d_in[30];
    float* out = (float*)d_out;

    char* ws = (char*)d_ws;
    float* p      = (float*)(ws + OFF_P);
    bf16*  qkvw_b = (bf16*)(ws + OFF_W);
    bf16*  prjw_b = (bf16*)(ws + OFF_W + SZ_QKVW);
    bf16*  m1w_b  = (bf16*)(ws + OFF_W + SZ_QKVW + SZ_PRJW);
    bf16*  m2w_b  = (bf16*)(ws + OFF_W + SZ_QKVW + SZ_PRJW + SZ_M1W);
    bf16*  h   = (bf16*)(ws + OFF_H);     // LN1 out -> ao -> mid
    bf16*  qb  = (bf16*)(ws + OFF_Q);
    bf16*  kb  = (bf16*)(ws + OFF_K);
    bf16*  vt  = (bf16*)(ws + OFF_V);
    bf16*  ao  = (bf16*)(ws + OFF_H);
    float* x1  = (float*)(ws + OFF_Q);    // spans q+k
    bf16*  h2  = (bf16*)(ws + OFF_V);
    bf16*  mid = (bf16*)(ws + OFF_H);

    // weight converts (f32 -> bf16)
    w_cvt<<<(2304*768/4+255)/256, 256, 0, stream>>>(qkv_w,  qkvw_b, 2304*768/4);
    w_cvt<<<( 768*768/4+255)/256, 256, 0, stream>>>(proj_w, prjw_b,  768*768/4);
    w_cvt<<<(3072*768/4+255)/256, 256, 0, stream>>>(m1_w,   m1w_b,  3072*768/4);
    w_cvt<<<(3072*768/4+255)/256, 256, 0, stream>>>(m2_w,   m2w_b,  3072*768/4);
    pos_mlp<<<841, 64, 0, stream>>>(biases, pp_w, pp_b, ln1_w, ln1_b, fcp1_w, fcp1_b,
                                    ln2_w, ln2_b, fcp2_w, fcp2_b, ln3_w, ln3_b, fcp3_w, fcp3_b, p);
    ln768<<<NROWS, 256, 0, stream>>>(x, norm1_w, norm1_b, h);
    gemm128<EPI_QKV><<<dim3(18, 99), 256, 0, stream>>>(
        h, DIMC, NROWS, qkvw_b, DIMC, DIMC, nullptr, nullptr, nullptr, nullptr, 0, qb, kb, vt);
    l2norm_qk<<<(NBATCH*NHEAD*NTOK*2)/4, 256, 0, stream>>>(qb, kb);
    attn_mfma<<<1600, 256, 0, stream>>>(qb, kb, vt, p, scale, pre_w, post_w, ao);
    gemm128<EPI_RES><<<dim3(6, 99), 256, 0, stream>>>(
        ao, DIMC, NROWS, prjw_b, DIMC, DIMC, proj_b, x, x1, nullptr, 0, nullptr, nullptr, nullptr);
    ln768<<<NROWS, 256, 0, stream>>>(x1, nrm2_w, nrm2_b, h2);
    for (int c=0; c<4; c++){
        gemm128<EPI_GELU><<<dim3(6, 99), 256, 0, stream>>>(
            h2, DIMC, NROWS, m1w_b + (size_t)c*768*DIMC, DIMC, DIMC, m1_b + c*768,
            nullptr, nullptr, mid, 768, nullptr, nullptr, nullptr);
        if (c < 3)
            gemm128<EPI_ACC><<<dim3(6, 99), 256, 0, stream>>>(
                mid, 768, NROWS, m2w_b + c*768, 3072, 768, nullptr, nullptr, x1, nullptr, 0,
                nullptr, nullptr, nullptr);
        else
            gemm128<EPI_RES><<<dim3(6, 99), 256, 0, stream>>>(
                mid, 768, NROWS, m2w_b + c*768, 3072, 768, m2_b, x1, out, nullptr, 0,
                nullptr, nullptr, nullptr);
    }
    (void)in_sizes; (void)n_in; (void)out_size; (void)ws_size;
}

// Round 6
// 891.349 us; speedup vs baseline: 1.8074x; 1.0405x over previous
//
#include <hip/hip_runtime.h>
#include <hip/hip_bf16.h>
#include <math.h>

typedef __hip_bfloat16 bf16;
typedef __attribute__((ext_vector_type(8))) short bf16x8;   // 8 bf16 (4 VGPRs)
typedef __attribute__((ext_vector_type(4))) float f32x4;

__device__ __forceinline__ float b2f(bf16 x){ return __bfloat162float(x); }
__device__ __forceinline__ bf16  f2b(float x){ return __float2bfloat16(x); }

// async global->LDS 16B (m97 pattern): LDS dest = wave-uniform base + lane*16
__device__ __forceinline__ void gld16(const bf16* g, bf16* l){
    __builtin_amdgcn_global_load_lds(
        (const __attribute__((address_space(1))) unsigned int*)g,
        (__attribute__((address_space(3))) unsigned int*)l, 16, 0, 0);
}

#define NTOK 197
#define NBATCH 64
#define NHEAD 8
#define DHEAD 96
#define DIMC 768
#define NROWS (NBATCH * NTOK)   // 12608
#define VTS 224                 // vt row stride (bf16), cols 197..223 zero-padded
#define SMS 208                 // LDS score row stride (f32) -> 52KB tile, 3 blocks/CU
#define MHALF 6304              // MLP row-chunk

// ---------------- workspace layout (bytes) ----------------
#define OFF_P   0ull
#define OFF_W   32768ull
#define SZ_QKVW 3538944ull
#define SZ_PRJW 1179648ull
#define SZ_M1W  4718592ull
#define SZ_M2W  4718592ull
#define OFF_H   14188544ull     // h -> ao -> mid(38.7MB spans OFF_H..OFF_K)
#define SZ_H    19365888ull
#define OFF_Q   33554432ull     // q
#define OFF_K   52920320ull     // k -> h2
#define OFF_V   72286208ull     // vt (22.02MB) -> x1b ; end 94,306,304 (< proven 96.9MB)

// ---------------- fused f32 -> bf16 weight convert (4 segments) ----------------
__global__ __launch_bounds__(256) void w_cvt_all(
    const float* __restrict__ s0, const float* __restrict__ s1,
    const float* __restrict__ s2, const float* __restrict__ s3, bf16* __restrict__ d)
{
    int i = blockIdx.x*256 + threadIdx.x;   // quad index, total 1,769,472
    const float* s; int off;
    if (i < 442368){ s=s0; off=i; }
    else if (i < 589824){ s=s1; off=i-442368; }
    else if (i < 1179648){ s=s2; off=i-589824; }
    else { s=s3; off=i-1179648; }
    float4 v = ((const float4*)s)[off];
    bf16 t[4] = {f2b(v.x), f2b(v.y), f2b(v.z), f2b(v.w)};
    ((ushort4*)d)[i] = *(ushort4*)t;
}

// ---------------- zero-pad vt cols 197..223 ----------------
__global__ __launch_bounds__(256) void vt_pad(bf16* __restrict__ vt){
    int i = blockIdx.x*256 + threadIdx.x;   // 49152 rows * 27 cols = 1,327,104
    if (i < 49152*27){
        int r = i/27, c = 197 + (i - r*27);
        vt[(size_t)r*VTS + c] = f2b(0.f);
    }
}

// ---------------- position-bias MLP (841 rows, tiny, all f32) ----------------
__global__ __launch_bounds__(64) void pos_mlp(
    const float* __restrict__ biases, const float* __restrict__ pp_w, const float* __restrict__ pp_b,
    const float* __restrict__ ln1w, const float* __restrict__ ln1b,
    const float* __restrict__ f1w,  const float* __restrict__ f1b,
    const float* __restrict__ ln2w, const float* __restrict__ ln2b,
    const float* __restrict__ f2w,  const float* __restrict__ f2b,
    const float* __restrict__ ln3w, const float* __restrict__ ln3b,
    const float* __restrict__ f3w,  const float* __restrict__ f3b,
    float* __restrict__ pout)
{
    const int row = blockIdx.x, j = threadIdx.x;
    __shared__ float va[48], vb[48];
    float b0 = biases[row*2], b1 = biases[row*2+1];
    if (j < 48) va[j] = b0*pp_w[j*2] + b1*pp_w[j*2+1] + pp_b[j];
    __syncthreads();
    {   float s=0.f, s2=0.f;
        for (int i=0;i<48;i++){ float t=va[i]; s+=t; s2+=t*t; }
        float mean=s*(1.f/48.f), var=s2*(1.f/48.f)-mean*mean, inv=rsqrtf(var+1e-5f);
        float r=0.f;
        if (j < 48){
            r = f1b[j];
            for (int i=0;i<48;i++){
                float t = fmaxf((va[i]-mean)*inv*ln1w[i] + ln1b[i], 0.f);
                r += t * f1w[j*48+i];
            }
        }
        __syncthreads();
        if (j < 48) vb[j] = r;
    }
    __syncthreads();
    {   float s=0.f, s2=0.f;
        for (int i=0;i<48;i++){ float t=vb[i]; s+=t; s2+=t*t; }
        float mean=s*(1.f/48.f), var=s2*(1.f/48.f)-mean*mean, inv=rsqrtf(var+1e-5f);
        float r=0.f;
        if (j < 48){
            r = f2b[j];
            for (int i=0;i<48;i++){
                float t = fmaxf((vb[i]-mean)*inv*ln2w[i] + ln2b[i], 0.f);
                r += t * f2w[j*48+i];
            }
        }
        __syncthreads();
        if (j < 48) va[j] = r;
    }
    __syncthreads();
    {   float s=0.f, s2=0.f;
        for (int i=0;i<48;i++){ float t=va[i]; s+=t; s2+=t*t; }
        float mean=s*(1.f/48.f), var=s2*(1.f/48.f)-mean*mean, inv=rsqrtf(var+1e-5f);
        if (j < 8){
            float r = f3b[j];
            for (int i=0;i<48;i++){
                float t = fmaxf((va[i]-mean)*inv*ln3w[i] + ln3b[i], 0.f);
                r += t * f3w[j*48+i];
            }
            pout[row*8+j] = r;
        }
    }
}

// ---------------- LayerNorm over 768 (f32 or bf16 in, bf16 out) ----------------
__device__ __forceinline__ float ldf(const bf16& x){ return __bfloat162float(x); }
__device__ __forceinline__ float ldf(const float& x){ return x; }

template<typename TIN>
__global__ __launch_bounds__(256) void ln768(
    const TIN* __restrict__ x, const float* __restrict__ w, const float* __restrict__ b,
    bf16* __restrict__ out)
{
    const int row = blockIdx.x, tid = threadIdx.x;
    const int wv = tid >> 6, ln = tid & 63;
    __shared__ float rs[4], rs2[4];
    const TIN* xr = x + (size_t)row * DIMC;
    float v0 = ldf(xr[tid]), v1 = ldf(xr[tid+256]), v2 = ldf(xr[tid+512]);
    float s = v0+v1+v2, s2 = v0*v0+v1*v1+v2*v2;
    #pragma unroll
    for (int off=32; off; off>>=1){ s += __shfl_xor(s,off,64); s2 += __shfl_xor(s2,off,64); }
    if (ln == 0){ rs[wv]=s; rs2[wv]=s2; }
    __syncthreads();
    s = rs[0]+rs[1]+rs[2]+rs[3]; s2 = rs2[0]+rs2[1]+rs2[2]+rs2[3];
    float mean = s*(1.f/768.f), var = s2*(1.f/768.f) - mean*mean;
    float inv = rsqrtf(var + 1e-5f);
    size_t base = (size_t)row * DIMC;
    out[base+tid]     = f2b((v0-mean)*inv*w[tid]     + b[tid]);
    out[base+tid+256] = f2b((v1-mean)*inv*w[tid+256] + b[tid+256]);
    out[base+tid+512] = f2b((v2-mean)*inv*w[tid+512] + b[tid+512]);
}

// ---------------- l2-normalize q,k rows (96 elems, bf16 in-place) ----------------
__global__ __launch_bounds__(256) void l2norm_qk(bf16* __restrict__ q, bf16* __restrict__ k)
{
    const int wv = threadIdx.x >> 6, ln = threadIdx.x & 63;
    const size_t NR = (size_t)NBATCH*NHEAD*NTOK;
    size_t row = (size_t)blockIdx.x * 4 + wv;
    bf16* ptr = (row < NR) ? (q + row*DHEAD) : (k + (row-NR)*DHEAD);
    float x0 = b2f(ptr[ln]);
    float x1 = (ln < 32) ? b2f(ptr[64+ln]) : 0.f;
    float ss = x0*x0 + x1*x1;
    #pragma unroll
    for (int off=32; off; off>>=1) ss += __shfl_xor(ss,off,64);
    float inv = 1.f / fmaxf(sqrtf(ss), 1e-12f);
    ptr[ln] = f2b(x0*inv);
    if (ln < 32) ptr[64+ln] = f2b(x1*inv);
}

// ---------------- MFMA attention: XCD-swizzled 1D grid, (batch, 8-token q-tile) ----------------
__global__ __launch_bounds__(256) void attn_mfma(
    const bf16* __restrict__ q, const bf16* __restrict__ k, const bf16* __restrict__ vt,
    const float* __restrict__ p, const float* __restrict__ scale,
    const float* __restrict__ pre_w, const float* __restrict__ post_w,
    bf16* __restrict__ ao)
{
    const int id = blockIdx.x;
    const int r8 = id & 7, t8 = id >> 3;
    const int bx = t8 % 25, b = r8 + 8*(t8/25);
    const int n0 = bx*8;
    const int tid = threadIdx.x, wv = tid>>6, ln = tid&63;
    const int fr = ln&15, fq = ln>>4;
    __shared__ float S[NHEAD*8*SMS];         // 53,248 B ; bf16 alias stride 416 after postmix
    __shared__ float s_pre[64], s_post[64], s_sc[8];
    bf16* Sb = (bf16*)S;
    if (tid < 64){ s_pre[tid]=pre_w[tid]; s_post[tid]=post_w[tid]; }
    if (tid < 8)  s_sc[tid] = fminf(scale[tid], 100.f);

    // ---- stage 1: raw scores S[h][nq][m] (13 K-tiles cover cols 0..207) with k prefetch
    #pragma unroll
    for (int hh=0; hh<2; hh++){
        const int h = wv + hh*4;
        int qr = n0 + fr; if (qr > 196) qr = 196;
        const bf16* qrow = q + ((size_t)(b*NHEAD+h)*NTOK + qr)*DHEAD + fq*8;
        bf16x8 a0 = *(const bf16x8*)(qrow);
        bf16x8 a1 = *(const bf16x8*)(qrow+32);
        bf16x8 a2 = *(const bf16x8*)(qrow+64);
        const bf16* kb0 = k + (size_t)(b*NHEAD+h)*NTOK*DHEAD + fq*8;
        const bf16* kr = kb0 + (size_t)fr*DHEAD;
        bf16x8 kv0 = *(const bf16x8*)(kr);
        bf16x8 kv1 = *(const bf16x8*)(kr+32);
        bf16x8 kv2 = *(const bf16x8*)(kr+64);
        for (int mt=0; mt<13; mt++){
            bf16x8 c0=kv0, c1=kv1, c2=kv2;
            if (mt < 12){
                int nr = (mt+1)*16+fr; if (nr>196) nr=196;
                const bf16* kn = kb0 + (size_t)nr*DHEAD;
                kv0 = *(const bf16x8*)(kn);
                kv1 = *(const bf16x8*)(kn+32);
                kv2 = *(const bf16x8*)(kn+64);
            }
            f32x4 acc = {};
            acc = __builtin_amdgcn_mfma_f32_16x16x32_bf16(a0, c0, acc,0,0,0);
            acc = __builtin_amdgcn_mfma_f32_16x16x32_bf16(a1, c1, acc,0,0,0);
            acc = __builtin_amdgcn_mfma_f32_16x16x32_bf16(a2, c2, acc,0,0,0);
            if (fq < 2){
                #pragma unroll
                for (int i=0;i<4;i++)
                    S[(h*8 + fq*4+i)*SMS + mt*16+fr] = acc[i];
            }
        }
    }
    __syncthreads();

    // ---- stage 2: scale + rel-pos bias + premix + geometric mask (cols 197..207 -> -1e9)
    const int sco[8] = {1,1,4,4,7,7,1000,1000};
    for (int c=tid; c<8*SMS; c+=256){
        int nq = c/SMS, m = c - nq*SMS;
        if (m >= 197){
            #pragma unroll
            for (int o=0;o<8;o++) S[(o*8+nq)*SMS+m] = -1e9f;
            continue;
        }
        int n = n0+nq; if (n > 196) n = 196;
        bool always = (n==0) || (m==0);
        int ri=0, ci=0, rj=0, cj=0;
        if (!always){
            ri=(n-1)/14; ci=(n-1)-ri*14;
            rj=(m-1)/14; cj=(m-1)-rj*14;
        }
        int dr = ri-rj; if (dr<0) dr=-dr;
        int dc = ci-cj; if (dc<0) dc=-dc;
        int idx = always ? 730 : (ri-rj+13)*27 + (ci-cj+13);
        const float* pv = p + idx*8;
        float sh[8];
        #pragma unroll
        for (int h=0;h<8;h++) sh[h] = S[(h*8+nq)*SMS+m]*s_sc[h] + pv[h];
        float ov[8];
        #pragma unroll
        for (int o=0;o<8;o++){
            float v=0.f;
            #pragma unroll
            for (int hh2=0;hh2<8;hh2++) v += s_pre[o*8+hh2]*sh[hh2];
            bool on = always || (dr<=sco[o] && dc<=sco[o]);
            ov[o] = on ? v : -1e9f;
        }
        #pragma unroll
        for (int o=0;o<8;o++) S[(o*8+nq)*SMS+m] = ov[o];
    }
    __syncthreads();

    // ---- stage 3: softmax per (o,nq) row over 208 cols — 64 rows, 16 per wave
    for (int r = wv*16; r < wv*16+16; r++){
        float* row = &S[r*SMS];
        float mx = -3e38f;
        for (int m=ln; m<SMS; m+=64) mx = fmaxf(mx, row[m]);
        #pragma unroll
        for (int off=32; off; off>>=1) mx = fmaxf(mx, __shfl_xor(mx,off,64));
        float sum = 0.f;
        for (int m=ln; m<SMS; m+=64){ float e=__expf(row[m]-mx); row[m]=e; sum+=e; }
        #pragma unroll
        for (int off=32; off; off>>=1) sum += __shfl_xor(sum,off,64);
        float inv = 1.f/sum;
        for (int m=ln; m<SMS; m+=64) row[m] *= inv;
    }
    __syncthreads();

    // ---- stage 3.5: postmix -> regs -> barrier -> bf16 in place (Sb stride 416)
    float ov[7][8];
    #pragma unroll
    for (int kk=0; kk<7; kk++){
        int c = tid + kk*256;
        if (c < 8*197){
            int nq = c/197, m = c - nq*197;
            float ph[8];
            #pragma unroll
            for (int o=0;o<8;o++) ph[o] = S[(o*8+nq)*SMS+m];
            #pragma unroll
            for (int o2=0;o2<8;o2++){
                float v=0.f;
                #pragma unroll
                for (int o=0;o<8;o++) v += s_post[o2*8+o]*ph[o];
                ov[kk][o2]=v;
            }
        }
    }
    __syncthreads();
    #pragma unroll
    for (int kk=0; kk<7; kk++){
        int c = tid + kk*256;
        if (c < 8*197){
            int nq = c/197, m = c - nq*197;
            #pragma unroll
            for (int o=0;o<8;o++) Sb[(o*8+nq)*416 + m] = f2b(ov[kk][o]);
        }
    }
    // zero P pad cols 197..223 (garbage bytes can alias to bf16 NaN; NaN*0=NaN in PV MFMA)
    for (int i=tid; i<64*27; i+=256){
        int r = i/27, mm = 197 + (i - (i/27)*27);
        Sb[r*416 + mm] = f2b(0.f);
    }
    __syncthreads();

    // ---- stage 4: P @ V via MFMA (A rows 8..15 dup; K-tiles cover 224 cols, V pad zero)
    const int frA = fr & 7;
    #pragma unroll
    for (int hh=0; hh<2; hh++){
        const int h = wv + hh*4;
        const bf16* vbase = vt + (size_t)(b*NHEAD+h)*DHEAD*VTS;
        for (int dt=0; dt<6; dt++){
            f32x4 acc = {};
            #pragma unroll
            for (int ks=0; ks<7; ks++){
                const bf16* ap = Sb + (h*8+frA)*416 + ks*32 + fq*8;
                const bf16* bp = vbase + (size_t)(dt*16+fr)*VTS + ks*32 + fq*8;
                acc = __builtin_amdgcn_mfma_f32_16x16x32_bf16(*(const bf16x8*)ap, *(const bf16x8*)bp, acc,0,0,0);
            }
            #pragma unroll
            for (int i=0;i<4;i++){
                int nq = fq*4+i, n = n0+nq;
                if (nq < 8 && n < NTOK)
                    ao[((size_t)b*NTOK+n)*DIMC + h*DHEAD + dt*16+fr] = f2b(acc[i]);
            }
        }
    }
}

// ---------------- m97-style MFMA GEMM: 128x128 tile, BK=32, global_load_lds ----------------
enum { EPI_QKV=0, EPI_X1=1, EPI_GELU=2, EPI_OUT=3 };

template<int EPI>
__global__ __launch_bounds__(256) void gemm128(
    const bf16* __restrict__ A, int lda, int M,
    const bf16* __restrict__ B, int ldb,
    int K,
    const float* __restrict__ bias,
    const float* __restrict__ resid_f,  // X1: x (f32)
    const bf16* __restrict__ resid_b,   // OUT: x1b
    float* __restrict__ dst_f,          // OUT: final out
    bf16* __restrict__ dst_b, int lddb, // X1: x1b ; GELU: mid
    int row_off,                        // OUT: global row offset
    bf16* __restrict__ qo, bf16* __restrict__ ko, bf16* __restrict__ vto)
{
    __shared__ bf16 As[128*32];
    __shared__ bf16 Bs[128*32];
    const int tid = threadIdx.x;
    const int wv = tid >> 6, ln = tid & 63;
    const int fr = ln & 15, fq = ln >> 4;
    const int wr = (wv & 1)*64, wc = (wv >> 1)*64;
    const int m0 = blockIdx.y*128, n0 = blockIdx.x*128;
    const int lnrow = ln >> 2, lncol = (ln & 3)*8;
    f32x4 acc[4][4] = {};
    for (int k0=0; k0<K; k0+=32){
        #pragma unroll
        for (int c=0;c<2;c++){
            int rA = m0 + (c*4+wv)*16 + lnrow;
            if (rA >= M) rA = M-1;
            gld16(A + (size_t)rA*lda + k0 + lncol, &As[(c*4+wv)*16*32]);
            int rB = n0 + (c*4+wv)*16 + lnrow;
            gld16(B + (size_t)rB*ldb + k0 + lncol, &Bs[(c*4+wv)*16*32]);
        }
        __syncthreads();
        bf16x8 af[4], bfv[4];
        #pragma unroll
        for (int i=0;i<4;i++){
            af[i]  = *(const bf16x8*)&As[(wr + i*16 + fr)*32 + fq*8];
            bfv[i] = *(const bf16x8*)&Bs[(wc + i*16 + fr)*32 + fq*8];
        }
        #pragma unroll
        for (int mi=0;mi<4;mi++)
            #pragma unroll
            for (int ni=0;ni<4;ni++)
                acc[mi][ni] = __builtin_amdgcn_mfma_f32_16x16x32_bf16(af[mi], bfv[ni], acc[mi][ni],0,0,0);
        __syncthreads();
    }
    #pragma unroll
    for (int mi=0;mi<4;mi++){
        #pragma unroll
        for (int ni=0;ni<4;ni++){
            #pragma unroll
            for (int i=0;i<4;i++){
                int row = m0 + wr + mi*16 + fq*4 + i;
                int col = n0 + wc + ni*16 + fr;
                if (row >= M) continue;
                float val = acc[mi][ni][i];
                if constexpr (EPI == EPI_QKV){
                    int which = col/768, rem = col - which*768;
                    int hh = rem/96, di = rem - hh*96;
                    int bb = row/NTOK, nn = row - bb*NTOK;
                    if (which == 0)      qo[(((size_t)bb*NHEAD+hh)*NTOK+nn)*DHEAD + di] = f2b(val);
                    else if (which == 1) ko[(((size_t)bb*NHEAD+hh)*NTOK+nn)*DHEAD + di] = f2b(val);
                    else                 vto[(((size_t)bb*NHEAD+hh)*DHEAD+di)*VTS + nn] = f2b(val);
                } else if constexpr (EPI == EPI_X1){
                    dst_b[(size_t)row*DIMC + col] = f2b(val + bias[col] + resid_f[(size_t)row*DIMC + col]);
                } else if constexpr (EPI == EPI_GELU){
                    float t = val + bias[col];
                    t = 0.5f*t*(1.f + erff(t*0.70710678118654752f));
                    dst_b[(size_t)row*lddb + col] = f2b(t);
                } else { // EPI_OUT
                    size_t g = (size_t)(row + row_off)*DIMC + col;
                    dst_f[g] = val + bias[col] + b2f(resid_b[g]);
                }
            }
        }
    }
}

extern "C" void kernel_launch(void* const* d_in, const int* in_sizes, int n_in,
                              void* d_out, int out_size, void* d_ws, size_t ws_size,
                              hipStream_t stream)
{
    const float* x        = (const float*)d_in[0];
    const float* norm1_w  = (const float*)d_in[1];
    const float* norm1_b  = (const float*)d_in[2];
    const float* qkv_w    = (const float*)d_in[3];
    const float* scale    = (const float*)d_in[4];
    const float* pp_w     = (const float*)d_in[5];
    const float* pp_b     = (const float*)d_in[6];
    const float* ln1_w    = (const float*)d_in[7];
    const float* ln1_b    = (const float*)d_in[8];
    const float* fcp1_w   = (const float*)d_in[9];
    const float* fcp1_b   = (const float*)d_in[10];
    const float* ln2_w    = (const float*)d_in[11];
    const float* ln2_b    = (const float*)d_in[12];
    const float* fcp2_w   = (const float*)d_in[13];
    const float* fcp2_b   = (const float*)d_in[14];
    const float* ln3_w    = (const float*)d_in[15];
    const float* ln3_b    = (const float*)d_in[16];
    const float* fcp3_w   = (const float*)d_in[17];
    const float* fcp3_b   = (const float*)d_in[18];
    const float* pre_w    = (const float*)d_in[19];
    const float* post_w   = (const float*)d_in[20];
    const float* proj_w   = (const float*)d_in[21];
    const float* proj_b   = (const float*)d_in[22];
    const float* nrm2_w   = (const float*)d_in[23];
    const float* nrm2_b   = (const float*)d_in[24];
    const float* m1_w     = (const float*)d_in[25];
    const float* m1_b     = (const float*)d_in[26];
    const float* m2_w     = (const float*)d_in[27];
    const float* m2_b     = (const float*)d_in[28];
    const float* biases   = (const float*)d_in[30];
    float* out = (float*)d_out;

    char* ws = (char*)d_ws;
    float* p      = (float*)(ws + OFF_P);
    bf16*  qkvw_b = (bf16*)(ws + OFF_W);
    bf16*  prjw_b = (bf16*)(ws + OFF_W + SZ_QKVW);
    bf16*  m1w_b  = (bf16*)(ws + OFF_W + SZ_QKVW + SZ_PRJW);
    bf16*  m2w_b  = (bf16*)(ws + OFF_W + SZ_QKVW + SZ_PRJW + SZ_M1W);
    bf16*  h   = (bf16*)(ws + OFF_H);     // LN1 out -> ao -> mid (spans OFF_H..OFF_K)
    bf16*  qb  = (bf16*)(ws + OFF_Q);
    bf16*  kb  = (bf16*)(ws + OFF_K);     // -> h2
    bf16*  vt  = (bf16*)(ws + OFF_V);     // -> x1b
    bf16*  ao  = (bf16*)(ws + OFF_H);
    bf16*  x1b = (bf16*)(ws + OFF_V);
    bf16*  h2  = (bf16*)(ws + OFF_K);
    bf16*  mid = (bf16*)(ws + OFF_H);     // 6304x3072 bf16 = 38.7MB

    w_cvt_all<<<6912, 256, 0, stream>>>(qkv_w, proj_w, m1_w, m2_w, qkvw_b);
    pos_mlp<<<841, 64, 0, stream>>>(biases, pp_w, pp_b, ln1_w, ln1_b, fcp1_w, fcp1_b,
                                    ln2_w, ln2_b, fcp2_w, fcp2_b, ln3_w, ln3_b, fcp3_w, fcp3_b, p);
    ln768<float><<<NROWS, 256, 0, stream>>>(x, norm1_w, norm1_b, h);
    gemm128<EPI_QKV><<<dim3(18, 99), 256, 0, stream>>>(
        h, DIMC, NROWS, qkvw_b, DIMC, DIMC, nullptr, nullptr, nullptr, nullptr,
        nullptr, 0, 0, qb, kb, vt);
    vt_pad<<<5184, 256, 0, stream>>>(vt);
    l2norm_qk<<<(NBATCH*NHEAD*NTOK*2)/4, 256, 0, stream>>>(qb, kb);
    attn_mfma<<<1600, 256, 0, stream>>>(qb, kb, vt, p, scale, pre_w, post_w, ao);
    gemm128<EPI_X1><<<dim3(6, 99), 256, 0, stream>>>(
        ao, DIMC, NROWS, prjw_b, DIMC, DIMC, proj_b, x, nullptr, nullptr,
        x1b, 0, 0, nullptr, nullptr, nullptr);
    ln768<bf16><<<NROWS, 256, 0, stream>>>(x1b, nrm2_w, nrm2_b, h2);
    for (int c=0; c<2; c++){
        const int r0 = c*MHALF;
        gemm128<EPI_GELU><<<dim3(24, 50), 256, 0, stream>>>(
            h2 + (size_t)r0*DIMC, DIMC, MHALF, m1w_b, DIMC, DIMC, m1_b,
            nullptr, nullptr, nullptr, mid, 3072, 0, nullptr, nullptr, nullptr);
        gemm128<EPI_OUT><<<dim3(6, 50), 256, 0, stream>>>(
            mid, 3072, MHALF, m2w_b, 3072, 3072, m2_b,
            nullptr, x1b, out, nullptr, 0, r0, nullptr, nullptr, nullptr);
    }
    (void)in_sizes; (void)n_in; (void)out_size; (void)ws_size;
}

// Round 7
// 846.420 us; speedup vs baseline: 1.9033x; 1.0531x over previous
//
#include <hip/hip_runtime.h>
#include <hip/hip_bf16.h>
#include <math.h>

typedef __hip_bfloat16 bf16;
typedef __attribute__((ext_vector_type(8))) short bf16x8;   // 8 bf16 (4 VGPRs)
typedef __attribute__((ext_vector_type(4))) float f32x4;

__device__ __forceinline__ float b2f(bf16 x){ return __bfloat162float(x); }
__device__ __forceinline__ bf16  f2b(float x){ return __float2bfloat16(x); }

// async global->LDS 16B (m97 pattern): LDS dest = wave-uniform base + lane*16
__device__ __forceinline__ void gld16(const bf16* g, bf16* l){
    __builtin_amdgcn_global_load_lds(
        (const __attribute__((address_space(1))) unsigned int*)g,
        (__attribute__((address_space(3))) unsigned int*)l, 16, 0, 0);
}

#define NTOK 197
#define NBATCH 64
#define NHEAD 8
#define DHEAD 96
#define DIMC 768
#define NROWS (NBATCH * NTOK)   // 12608
#define VTS 224                 // vt row stride (bf16), cols 197..223 zero-padded (by QKV epilogue)
#define SMS 228                 // LDS score row stride (f32): R4 banking (stage-4 ~2-way)
#define MHALF 6304              // MLP row-chunk

// ---------------- workspace layout (bytes) ----------------
#define OFF_P   0ull
#define OFF_W   32768ull
#define SZ_QKVW 3538944ull
#define SZ_PRJW 1179648ull
#define SZ_M1W  4718592ull
#define SZ_M2W  4718592ull
#define OFF_H   14188544ull     // h -> ao -> mid(38.7MB spans OFF_H..OFF_K)
#define SZ_H    19365888ull
#define OFF_Q   33554432ull     // q
#define OFF_K   52920320ull     // k -> h2
#define OFF_V   72286208ull     // vt (22.02MB) -> x1b ; end 94,306,304 (< proven 96.9MB)

// ---------------- fused f32 -> bf16 weight convert (4 segments) ----------------
__global__ __launch_bounds__(256) void w_cvt_all(
    const float* __restrict__ s0, const float* __restrict__ s1,
    const float* __restrict__ s2, const float* __restrict__ s3, bf16* __restrict__ d)
{
    int i = blockIdx.x*256 + threadIdx.x;   // quad index, total 1,769,472
    const float* s; int off;
    if (i < 442368){ s=s0; off=i; }
    else if (i < 589824){ s=s1; off=i-442368; }
    else if (i < 1179648){ s=s2; off=i-589824; }
    else { s=s3; off=i-1179648; }
    float4 v = ((const float4*)s)[off];
    bf16 t[4] = {f2b(v.x), f2b(v.y), f2b(v.z), f2b(v.w)};
    ((ushort4*)d)[i] = *(ushort4*)t;
}

// ---------------- position-bias MLP (841 rows, tiny, all f32) ----------------
__global__ __launch_bounds__(64) void pos_mlp(
    const float* __restrict__ biases, const float* __restrict__ pp_w, const float* __restrict__ pp_b,
    const float* __restrict__ ln1w, const float* __restrict__ ln1b,
    const float* __restrict__ f1w,  const float* __restrict__ f1b,
    const float* __restrict__ ln2w, const float* __restrict__ ln2b,
    const float* __restrict__ f2w,  const float* __restrict__ f2b,
    const float* __restrict__ ln3w, const float* __restrict__ ln3b,
    const float* __restrict__ f3w,  const float* __restrict__ f3b,
    float* __restrict__ pout)
{
    const int row = blockIdx.x, j = threadIdx.x;
    __shared__ float va[48], vb[48];
    float b0 = biases[row*2], b1 = biases[row*2+1];
    if (j < 48) va[j] = b0*pp_w[j*2] + b1*pp_w[j*2+1] + pp_b[j];
    __syncthreads();
    {   float s=0.f, s2=0.f;
        for (int i=0;i<48;i++){ float t=va[i]; s+=t; s2+=t*t; }
        float mean=s*(1.f/48.f), var=s2*(1.f/48.f)-mean*mean, inv=rsqrtf(var+1e-5f);
        float r=0.f;
        if (j < 48){
            r = f1b[j];
            for (int i=0;i<48;i++){
                float t = fmaxf((va[i]-mean)*inv*ln1w[i] + ln1b[i], 0.f);
                r += t * f1w[j*48+i];
            }
        }
        __syncthreads();
        if (j < 48) vb[j] = r;
    }
    __syncthreads();
    {   float s=0.f, s2=0.f;
        for (int i=0;i<48;i++){ float t=vb[i]; s+=t; s2+=t*t; }
        float mean=s*(1.f/48.f), var=s2*(1.f/48.f)-mean*mean, inv=rsqrtf(var+1e-5f);
        float r=0.f;
        if (j < 48){
            r = f2b[j];
            for (int i=0;i<48;i++){
                float t = fmaxf((vb[i]-mean)*inv*ln2w[i] + ln2b[i], 0.f);
                r += t * f2w[j*48+i];
            }
        }
        __syncthreads();
        if (j < 48) va[j] = r;
    }
    __syncthreads();
    {   float s=0.f, s2=0.f;
        for (int i=0;i<48;i++){ float t=va[i]; s+=t; s2+=t*t; }
        float mean=s*(1.f/48.f), var=s2*(1.f/48.f)-mean*mean, inv=rsqrtf(var+1e-5f);
        if (j < 8){
            float r = f3b[j];
            for (int i=0;i<48;i++){
                float t = fmaxf((va[i]-mean)*inv*ln3w[i] + ln3b[i], 0.f);
                r += t * f3w[j*48+i];
            }
            pout[row*8+j] = r;
        }
    }
}

// ---------------- LayerNorm over 768 (f32 or bf16 in, bf16 out) ----------------
__device__ __forceinline__ float ldf(const bf16& x){ return __bfloat162float(x); }
__device__ __forceinline__ float ldf(const float& x){ return x; }

template<typename TIN>
__global__ __launch_bounds__(256) void ln768(
    const TIN* __restrict__ x, const float* __restrict__ w, const float* __restrict__ b,
    bf16* __restrict__ out)
{
    const int row = blockIdx.x, tid = threadIdx.x;
    const int wv = tid >> 6, ln = tid & 63;
    __shared__ float rs[4], rs2[4];
    const TIN* xr = x + (size_t)row * DIMC;
    float v0 = ldf(xr[tid]), v1 = ldf(xr[tid+256]), v2 = ldf(xr[tid+512]);
    float s = v0+v1+v2, s2 = v0*v0+v1*v1+v2*v2;
    #pragma unroll
    for (int off=32; off; off>>=1){ s += __shfl_xor(s,off,64); s2 += __shfl_xor(s2,off,64); }
    if (ln == 0){ rs[wv]=s; rs2[wv]=s2; }
    __syncthreads();
    s = rs[0]+rs[1]+rs[2]+rs[3]; s2 = rs2[0]+rs2[1]+rs2[2]+rs2[3];
    float mean = s*(1.f/768.f), var = s2*(1.f/768.f) - mean*mean;
    float inv = rsqrtf(var + 1e-5f);
    size_t base = (size_t)row * DIMC;
    out[base+tid]     = f2b((v0-mean)*inv*w[tid]     + b[tid]);
    out[base+tid+256] = f2b((v1-mean)*inv*w[tid+256] + b[tid+256]);
    out[base+tid+512] = f2b((v2-mean)*inv*w[tid+512] + b[tid+512]);
}

// ---------------- l2-normalize q,k rows (96 elems, bf16 in-place) ----------------
__global__ __launch_bounds__(256) void l2norm_qk(bf16* __restrict__ q, bf16* __restrict__ k)
{
    const int wv = threadIdx.x >> 6, ln = threadIdx.x & 63;
    const size_t NR = (size_t)NBATCH*NHEAD*NTOK;
    size_t row = (size_t)blockIdx.x * 4 + wv;
    bf16* ptr = (row < NR) ? (q + row*DHEAD) : (k + (row-NR)*DHEAD);
    float x0 = b2f(ptr[ln]);
    float x1 = (ln < 32) ? b2f(ptr[64+ln]) : 0.f;
    float ss = x0*x0 + x1*x1;
    #pragma unroll
    for (int off=32; off; off>>=1) ss += __shfl_xor(ss,off,64);
    float inv = 1.f / fmaxf(sqrtf(ss), 1e-12f);
    ptr[ln] = f2b(x0*inv);
    if (ln < 32) ptr[64+ln] = f2b(x1*inv);
}

// ---------------- MFMA attention: XCD-swizzled 1D grid, (batch, 8-token q-tile) ----------------
__global__ __launch_bounds__(256) void attn_mfma(
    const bf16* __restrict__ q, const bf16* __restrict__ k, const bf16* __restrict__ vt,
    const float* __restrict__ p, const float* __restrict__ scale,
    const float* __restrict__ pre_w, const float* __restrict__ post_w,
    bf16* __restrict__ ao)
{
    const int id = blockIdx.x;
    const int r8 = id & 7, t8 = id >> 3;
    const int bx = t8 % 25, b = r8 + 8*(t8/25);
    const int n0 = bx*8;
    const int tid = threadIdx.x, wv = tid>>6, ln = tid&63;
    const int fr = ln&15, fq = ln>>4;
    __shared__ float S[NHEAD*8*SMS];         // 58,368 B ; bf16 alias stride 456 after postmix
    __shared__ float s_pre[64], s_post[64], s_sc[8];
    bf16* Sb = (bf16*)S;
    if (tid < 64){ s_pre[tid]=pre_w[tid]; s_post[tid]=post_w[tid]; }
    if (tid < 8)  s_sc[tid] = fminf(scale[tid], 100.f);

    // ---- stage 1: raw scores S[h][nq][m] (13 K-tiles cover cols 0..207) with k prefetch
    #pragma unroll
    for (int hh=0; hh<2; hh++){
        const int h = wv + hh*4;
        int qr = n0 + fr; if (qr > 196) qr = 196;
        const bf16* qrow = q + ((size_t)(b*NHEAD+h)*NTOK + qr)*DHEAD + fq*8;
        bf16x8 a0 = *(const bf16x8*)(qrow);
        bf16x8 a1 = *(const bf16x8*)(qrow+32);
        bf16x8 a2 = *(const bf16x8*)(qrow+64);
        const bf16* kb0 = k + (size_t)(b*NHEAD+h)*NTOK*DHEAD + fq*8;
        const bf16* kr = kb0 + (size_t)fr*DHEAD;
        bf16x8 kv0 = *(const bf16x8*)(kr);
        bf16x8 kv1 = *(const bf16x8*)(kr+32);
        bf16x8 kv2 = *(const bf16x8*)(kr+64);
        for (int mt=0; mt<13; mt++){
            bf16x8 c0=kv0, c1=kv1, c2=kv2;
            if (mt < 12){
                int nr = (mt+1)*16+fr; if (nr>196) nr=196;
                const bf16* kn = kb0 + (size_t)nr*DHEAD;
                kv0 = *(const bf16x8*)(kn);
                kv1 = *(const bf16x8*)(kn+32);
                kv2 = *(const bf16x8*)(kn+64);
            }
            f32x4 acc = {};
            acc = __builtin_amdgcn_mfma_f32_16x16x32_bf16(a0, c0, acc,0,0,0);
            acc = __builtin_amdgcn_mfma_f32_16x16x32_bf16(a1, c1, acc,0,0,0);
            acc = __builtin_amdgcn_mfma_f32_16x16x32_bf16(a2, c2, acc,0,0,0);
            if (fq < 2){
                #pragma unroll
                for (int i=0;i<4;i++)
                    S[(h*8 + fq*4+i)*SMS + mt*16+fr] = acc[i];
            }
        }
    }
    __syncthreads();

    // ---- stage 2: scale + rel-pos bias + premix + geometric mask (cols 197..223 -> -1e9)
    const int sco[8] = {1,1,4,4,7,7,1000,1000};
    for (int c=tid; c<8*224; c+=256){
        int nq = c/224, m = c - nq*224;
        if (m >= 197){
            #pragma unroll
            for (int o=0;o<8;o++) S[(o*8+nq)*SMS+m] = -1e9f;
            continue;
        }
        int n = n0+nq; if (n > 196) n = 196;
        bool always = (n==0) || (m==0);
        int ri=0, ci=0, rj=0, cj=0;
        if (!always){
            ri=(n-1)/14; ci=(n-1)-ri*14;
            rj=(m-1)/14; cj=(m-1)-rj*14;
        }
        int dr = ri-rj; if (dr<0) dr=-dr;
        int dc = ci-cj; if (dc<0) dc=-dc;
        int idx = always ? 730 : (ri-rj+13)*27 + (ci-cj+13);
        const float* pv = p + idx*8;
        float sh[8];
        #pragma unroll
        for (int h=0;h<8;h++) sh[h] = S[(h*8+nq)*SMS+m]*s_sc[h] + pv[h];
        float ov[8];
        #pragma unroll
        for (int o=0;o<8;o++){
            float v=0.f;
            #pragma unroll
            for (int hh2=0;hh2<8;hh2++) v += s_pre[o*8+hh2]*sh[hh2];
            bool on = always || (dr<=sco[o] && dc<=sco[o]);
            ov[o] = on ? v : -1e9f;
        }
        #pragma unroll
        for (int o=0;o<8;o++) S[(o*8+nq)*SMS+m] = ov[o];
    }
    __syncthreads();

    // ---- stage 3: softmax per (o,nq) row over 224 cols — 64 rows, 16 per wave
    for (int r = wv*16; r < wv*16+16; r++){
        float* row = &S[r*SMS];
        float mx = -3e38f;
        for (int m=ln; m<224; m+=64) mx = fmaxf(mx, row[m]);
        #pragma unroll
        for (int off=32; off; off>>=1) mx = fmaxf(mx, __shfl_xor(mx,off,64));
        float sum = 0.f;
        for (int m=ln; m<224; m+=64){ float e=__expf(row[m]-mx); row[m]=e; sum+=e; }
        #pragma unroll
        for (int off=32; off; off>>=1) sum += __shfl_xor(sum,off,64);
        float inv = 1.f/sum;
        for (int m=ln; m<224; m+=64) row[m] *= inv;
    }
    __syncthreads();

    // ---- stage 3.5: postmix -> regs -> barrier -> bf16 in place (Sb stride 456)
    float ov[7][8];
    #pragma unroll
    for (int kk=0; kk<7; kk++){
        int c = tid + kk*256;
        if (c < 8*197){
            int nq = c/197, m = c - nq*197;
            float ph[8];
            #pragma unroll
            for (int o=0;o<8;o++) ph[o] = S[(o*8+nq)*SMS+m];
            #pragma unroll
            for (int o2=0;o2<8;o2++){
                float v=0.f;
                #pragma unroll
                for (int o=0;o<8;o++) v += s_post[o2*8+o]*ph[o];
                ov[kk][o2]=v;
            }
        }
    }
    __syncthreads();
    #pragma unroll
    for (int kk=0; kk<7; kk++){
        int c = tid + kk*256;
        if (c < 8*197){
            int nq = c/197, m = c - nq*197;
            #pragma unroll
            for (int o=0;o<8;o++) Sb[(o*8+nq)*456 + m] = f2b(ov[kk][o]);
        }
    }
    // zero P pad cols 197..223 (garbage bytes can alias to bf16 NaN; NaN*0=NaN in PV MFMA)
    for (int i=tid; i<64*27; i+=256){
        int r = i/27, mm = 197 + (i - (i/27)*27);
        Sb[r*456 + mm] = f2b(0.f);
    }
    __syncthreads();

    // ---- stage 4: P @ V via MFMA (A rows 8..15 dup; K-tiles cover 224 cols, V pad zero)
    const int frA = fr & 7;
    #pragma unroll
    for (int hh=0; hh<2; hh++){
        const int h = wv + hh*4;
        const bf16* vbase = vt + (size_t)(b*NHEAD+h)*DHEAD*VTS;
        for (int dt=0; dt<6; dt++){
            f32x4 acc = {};
            #pragma unroll
            for (int ks=0; ks<7; ks++){
                const bf16* ap = Sb + (h*8+frA)*456 + ks*32 + fq*8;
                const bf16* bp = vbase + (size_t)(dt*16+fr)*VTS + ks*32 + fq*8;
                acc = __builtin_amdgcn_mfma_f32_16x16x32_bf16(*(const bf16x8*)ap, *(const bf16x8*)bp, acc,0,0,0);
            }
            #pragma unroll
            for (int i=0;i<4;i++){
                int nq = fq*4+i, n = n0+nq;
                if (nq < 8 && n < NTOK)
                    ao[((size_t)b*NTOK+n)*DIMC + h*DHEAD + dt*16+fr] = f2b(acc[i]);
            }
        }
    }
}

// ---------------- m97-style MFMA GEMM: 128x128 tile, BK=64 (2x 128x32 sub-tiles) ----------------
enum { EPI_QKV=0, EPI_X1=1, EPI_GELU=2, EPI_OUT=3 };

template<int EPI>
__global__ __launch_bounds__(256) void gemm128(
    const bf16* __restrict__ A, int lda, int M,
    const bf16* __restrict__ B, int ldb,
    int K,
    const float* __restrict__ bias,
    const float* __restrict__ resid_f,  // X1: x (f32)
    const bf16* __restrict__ resid_b,   // OUT: x1b
    float* __restrict__ dst_f,          // OUT: final out
    bf16* __restrict__ dst_b, int lddb, // X1: x1b ; GELU: mid
    int row_off,                        // OUT: global row offset
    bf16* __restrict__ qo, bf16* __restrict__ ko, bf16* __restrict__ vto)
{
    __shared__ bf16 As[2*128*32];   // two K-32 sub-tiles
    __shared__ bf16 Bs[2*128*32];
    const int tid = threadIdx.x;
    const int wv = tid >> 6, ln = tid & 63;
    const int fr = ln & 15, fq = ln >> 4;
    const int wr = (wv & 1)*64, wc = (wv >> 1)*64;
    const int m0 = blockIdx.y*128, n0 = blockIdx.x*128;
    const int lnrow = ln >> 2, lncol = (ln & 3)*8;
    f32x4 acc[4][4] = {};
    for (int k0=0; k0<K; k0+=64){
        #pragma unroll
        for (int t=0;t<2;t++){
            #pragma unroll
            for (int c=0;c<2;c++){
                int rA = m0 + (c*4+wv)*16 + lnrow;
                if (rA >= M) rA = M-1;
                gld16(A + (size_t)rA*lda + k0 + t*32 + lncol, &As[t*4096 + (c*4+wv)*16*32]);
                int rB = n0 + (c*4+wv)*16 + lnrow;
                gld16(B + (size_t)rB*ldb + k0 + t*32 + lncol, &Bs[t*4096 + (c*4+wv)*16*32]);
            }
        }
        __syncthreads();
        #pragma unroll
        for (int t=0;t<2;t++){
            bf16x8 af[4], bfv[4];
            #pragma unroll
            for (int i=0;i<4;i++){
                af[i]  = *(const bf16x8*)&As[t*4096 + (wr + i*16 + fr)*32 + fq*8];
                bfv[i] = *(const bf16x8*)&Bs[t*4096 + (wc + i*16 + fr)*32 + fq*8];
            }
            #pragma unroll
            for (int mi=0;mi<4;mi++)
                #pragma unroll
                for (int ni=0;ni<4;ni++)
                    acc[mi][ni] = __builtin_amdgcn_mfma_f32_16x16x32_bf16(af[mi], bfv[ni], acc[mi][ni],0,0,0);
        }
        __syncthreads();
    }
    #pragma unroll
    for (int mi=0;mi<4;mi++){
        #pragma unroll
        for (int ni=0;ni<4;ni++){
            #pragma unroll
            for (int i=0;i<4;i++){
                int row = m0 + wr + mi*16 + fq*4 + i;
                int col = n0 + wc + ni*16 + fr;
                if (row >= M) continue;
                float val = acc[mi][ni][i];
                if constexpr (EPI == EPI_QKV){
                    int which = col/768, rem = col - which*768;
                    int hh = rem/96, di = rem - hh*96;
                    int bb = row/NTOK, nn = row - bb*NTOK;
                    if (which == 0)      qo[(((size_t)bb*NHEAD+hh)*NTOK+nn)*DHEAD + di] = f2b(val);
                    else if (which == 1) ko[(((size_t)bb*NHEAD+hh)*NTOK+nn)*DHEAD + di] = f2b(val);
                    else {
                        vto[(((size_t)bb*NHEAD+hh)*DHEAD+di)*VTS + nn] = f2b(val);
                        if (nn < VTS - NTOK)   // fused vt pad-zero (cols 197..223)
                            vto[(((size_t)bb*NHEAD+hh)*DHEAD+di)*VTS + NTOK + nn] = f2b(0.f);
                    }
                } else if constexpr (EPI == EPI_X1){
                    dst_b[(size_t)row*DIMC + col] = f2b(val + bias[col] + resid_f[(size_t)row*DIMC + col]);
                } else if constexpr (EPI == EPI_GELU){
                    float t = val + bias[col];
                    t = 0.5f*t*(1.f + erff(t*0.70710678118654752f));
                    dst_b[(size_t)row*lddb + col] = f2b(t);
                } else { // EPI_OUT
                    size_t g = (size_t)(row + row_off)*DIMC + col;
                    dst_f[g] = val + bias[col] + b2f(resid_b[g]);
                }
            }
        }
    }
}

extern "C" void kernel_launch(void* const* d_in, const int* in_sizes, int n_in,
                              void* d_out, int out_size, void* d_ws, size_t ws_size,
                              hipStream_t stream)
{
    const float* x        = (const float*)d_in[0];
    const float* norm1_w  = (const float*)d_in[1];
    const float* norm1_b  = (const float*)d_in[2];
    const float* qkv_w    = (const float*)d_in[3];
    const float* scale    = (const float*)d_in[4];
    const float* pp_w     = (const float*)d_in[5];
    const float* pp_b     = (const float*)d_in[6];
    const float* ln1_w    = (const float*)d_in[7];
    const float* ln1_b    = (const float*)d_in[8];
    const float* fcp1_w   = (const float*)d_in[9];
    const float* fcp1_b   = (const float*)d_in[10];
    const float* ln2_w    = (const float*)d_in[11];
    const float* ln2_b    = (const float*)d_in[12];
    const float* fcp2_w   = (const float*)d_in[13];
    const float* fcp2_b   = (const float*)d_in[14];
    const float* ln3_w    = (const float*)d_in[15];
    const float* ln3_b    = (const float*)d_in[16];
    const float* fcp3_w   = (const float*)d_in[17];
    const float* fcp3_b   = (const float*)d_in[18];
    const float* pre_w    = (const float*)d_in[19];
    const float* post_w   = (const float*)d_in[20];
    const float* proj_w   = (const float*)d_in[21];
    const float* proj_b   = (const float*)d_in[22];
    const float* nrm2_w   = (const float*)d_in[23];
    const float* nrm2_b   = (const float*)d_in[24];
    const float* m1_w     = (const float*)d_in[25];
    const float* m1_b     = (const float*)d_in[26];
    const float* m2_w     = (const float*)d_in[27];
    const float* m2_b     = (const float*)d_in[28];
    const float* biases   = (const float*)d_in[30];
    float* out = (float*)d_out;

    char* ws = (char*)d_ws;
    float* p      = (float*)(ws + OFF_P);
    bf16*  qkvw_b = (bf16*)(ws + OFF_W);
    bf16*  prjw_b = (bf16*)(ws + OFF_W + SZ_QKVW);
    bf16*  m1w_b  = (bf16*)(ws + OFF_W + SZ_QKVW + SZ_PRJW);
    bf16*  m2w_b  = (bf16*)(ws + OFF_W + SZ_QKVW + SZ_PRJW + SZ_M1W);
    bf16*  h   = (bf16*)(ws + OFF_H);     // LN1 out -> ao -> mid (spans OFF_H..OFF_K)
    bf16*  qb  = (bf16*)(ws + OFF_Q);
    bf16*  kb  = (bf16*)(ws + OFF_K);     // -> h2
    bf16*  vt  = (bf16*)(ws + OFF_V);     // -> x1b
    bf16*  ao  = (bf16*)(ws + OFF_H);
    bf16*  x1b = (bf16*)(ws + OFF_V);
    bf16*  h2  = (bf16*)(ws + OFF_K);
    bf16*  mid = (bf16*)(ws + OFF_H);     // 6304x3072 bf16 = 38.7MB

    w_cvt_all<<<6912, 256, 0, stream>>>(qkv_w, proj_w, m1_w, m2_w, qkvw_b);
    pos_mlp<<<841, 64, 0, stream>>>(biases, pp_w, pp_b, ln1_w, ln1_b, fcp1_w, fcp1_b,
                                    ln2_w, ln2_b, fcp2_w, fcp2_b, ln3_w, ln3_b, fcp3_w, fcp3_b, p);
    ln768<float><<<NROWS, 256, 0, stream>>>(x, norm1_w, norm1_b, h);
    gemm128<EPI_QKV><<<dim3(18, 99), 256, 0, stream>>>(
        h, DIMC, NROWS, qkvw_b, DIMC, DIMC, nullptr, nullptr, nullptr, nullptr,
        nullptr, 0, 0, qb, kb, vt);
    l2norm_qk<<<(NBATCH*NHEAD*NTOK*2)/4, 256, 0, stream>>>(qb, kb);
    attn_mfma<<<1600, 256, 0, stream>>>(qb, kb, vt, p, scale, pre_w, post_w, ao);
    gemm128<EPI_X1><<<dim3(6, 99), 256, 0, stream>>>(
        ao, DIMC, NROWS, prjw_b, DIMC, DIMC, proj_b, x, nullptr, nullptr,
        x1b, 0, 0, nullptr, nullptr, nullptr);
    ln768<bf16><<<NROWS, 256, 0, stream>>>(x1b, nrm2_w, nrm2_b, h2);
    for (int c=0; c<2; c++){
        const int r0 = c*MHALF;
        gemm128<EPI_GELU><<<dim3(24, 50), 256, 0, stream>>>(
            h2 + (size_t)r0*DIMC, DIMC, MHALF, m1w_b, DIMC, DIMC, m1_b,
            nullptr, nullptr, nullptr, mid, 3072, 0, nullptr, nullptr, nullptr);
        gemm128<EPI_OUT><<<dim3(6, 50), 256, 0, stream>>>(
            mid, 3072, MHALF, m2w_b, 3072, 3072, m2_b,
            nullptr, x1b, out, nullptr, 0, r0, nullptr, nullptr, nullptr);
    }
    (void)in_sizes; (void)n_in; (void)out_size; (void)ws_size;
}